// Round 3
// baseline (100.439 us; speedup 1.0000x reference)
//
#include <hip/hip_runtime.h>
#include <math.h>

#define BATCH 256
#define M 48
#define T 80
#define NF 6
#define EMIT 10
#define MM (M*M)        // 2304
#define NTH 512         // 8 waves/block -> 2 waves/SIMD
#define NK 5            // ceil(2304/512); 5th key valid only for tid<256
#define LOG2PI 1.8378770664093453f

typedef unsigned int u32;
typedef unsigned long long u64;

// Raw workgroup sync: drains LDS (lgkm) only -- async global_load_lds DMA
// (vmcnt) stays in flight. "memory" clobber stops compiler caching LDS in regs.
#define WGSYNC()     __asm__ __volatile__("s_waitcnt lgkmcnt(0)\ns_barrier" ::: "memory")
#define WGSYNC_ALL() __asm__ __volatile__("s_waitcnt vmcnt(0) lgkmcnt(0)\ns_barrier" ::: "memory")

// 8 waves/block. PROLOGUE FIX this round: all waves issue their (redundant,
// cache-served) selector gathers BEFORE the DMA chunks -- vmcnt is a FIFO, so
// consuming the gathers now drains only the 7 oldest loads instead of the
// wave's ~12 DMA chunks (round 2 convoyed every wave behind wave 0's DMA at
// the first barrier). Staging + softmax redundant on all waves (identical
// writes, race-safe). Everything after the first WGSYNC unchanged: split keys/
// radix/adjacency, wave-0 greedy, split E-step (384 lanes), split M-step.
__global__ __launch_bounds__(NTH, 1)
void em_kernel(const float* __restrict__ g_logits,
               const float* __restrict__ g_traj,
               const float* __restrict__ g_cov,
               float* __restrict__ g_out)
{
    const int b = blockIdx.x;
    const int tid = threadIdx.x;
    const int lane = tid & 63;
    const int wv = tid >> 6;          // 0..7
    const int SEL[3] = {29, 49, 79};

    // ---- LDS ~110 KB ----
    __shared__ __align__(16) float s_txy[M*T*2];   // staged traj (DMA)
    __shared__ __align__(16) float s_cv4[M*T*4];   // staged cov (DMA)
    __shared__ float s_adj[MM];
    __shared__ float s_logits[M];
    __shared__ float s_probas[M];
    __shared__ float s_tsel[M*6];                  // [m][tt][d]
    __shared__ float s_d1[M*3];
    __shared__ __align__(16) float s_csel[M*3*4];  // [m][tt]{c00,c01,c11,pad}
    __shared__ __align__(16) float s_Pm[M*8];      // slots: 0-2=n0..2, 4-6=n3..5
    __shared__ float s_t6sel[2][NF*6];             // ping-pong EM state
    __shared__ float s_probas6[2][NF];
    __shared__ float s_prec[2][NF*3*3];
    __shared__ float s_ld[2][NF*3];
    __shared__ int   s_idx[8];
    __shared__ __align__(16) u32 s_hist[4][256];   // shared per-round hists
    __shared__ u32 s_statc[8], s_statm[8];

    const float* traj_b = g_traj + (size_t)b*(M*T*2);
    const float* cov_b  = g_cov  + (size_t)b*(M*T*4);

    // ========== direct gathers FIRST (redundant per wave; oldest vmem ops) ====
    float myLogit = -1e30f;
    if (lane < M) myLogit = g_logits[b*M + lane];
    float selx[3], sely[3], cc0[3], cc1[3], cc2[3];
    #pragma unroll
    for (int r = 0; r < 3; ++r) {
        int i = lane + r*64;
        if (i < M*3) {
            int m = i/3, tt = i - (i/3)*3;
            float2 xy = ((const float2*)traj_b)[m*T + SEL[tt]];
            float4 cv = ((const float4*)cov_b)[m*T + SEL[tt]];
            selx[r]=xy.x; sely[r]=xy.y; cc0[r]=cv.x; cc1[r]=cv.y; cc2[r]=cv.w;
        }
    }

    // ========== DMA staging AFTER gathers, split 8 ways ==========
    __builtin_amdgcn_sched_barrier(0);
    {
        const char* gt = (const char*)traj_b + lane*16;
        char* lt = (char*)s_txy;
        #pragma unroll 2
        for (int k = wv; k < 30; k += 8)
            __builtin_amdgcn_global_load_lds(
                (const __attribute__((address_space(1))) u32*)(gt + k*1024),
                (__attribute__((address_space(3))) u32*)(lt + k*1024), 16, 0, 0);
        const char* gc = (const char*)cov_b + lane*16;
        char* lc = (char*)s_cv4;
        #pragma unroll 2
        for (int k = wv; k < 60; k += 8)
            __builtin_amdgcn_global_load_lds(
                (const __attribute__((address_space(1))) u32*)(gc + k*1024),
                (__attribute__((address_space(3))) u32*)(lc + k*1024), 16, 0, 0);
    }
    __builtin_amdgcn_sched_barrier(0);

    // ========== zero shared hists ==========
    if (tid < 256) ((uint4*)s_hist)[tid] = make_uint4(0,0,0,0);

    // ========== stage selector data (redundant identical writes) ==========
    if (lane < M) s_logits[lane] = myLogit;
    #pragma unroll
    for (int r = 0; r < 3; ++r) {
        int i = lane + r*64;
        if (i < M*3) {
            int m = i/3, tt = i - (i/3)*3;
            s_tsel[m*6+tt*2+0] = selx[r];
            s_tsel[m*6+tt*2+1] = sely[r];
            s_d1[i] = selx[r]*selx[r] + sely[r]*sely[r];
            s_csel[i*4+0]=cc0[r]; s_csel[i*4+1]=cc1[r]; s_csel[i*4+2]=cc2[r]; s_csel[i*4+3]=0.f;
        }
    }

    // ========== softmax (in-wave, registers; redundant per wave) ==========
    float mx = myLogit;
    #pragma unroll
    for (int off = 32; off; off >>= 1) mx = fmaxf(mx, __shfl_xor(mx, off));
    float pe = (lane < M) ? __expf(myLogit - mx) : 0.f;
    float psum = pe;
    #pragma unroll
    for (int off = 32; off; off >>= 1) psum += __shfl_xor(psum, off);
    if (lane < M) s_probas[lane] = pe / psum;

    WGSYNC();   // staging + softmax + hist zeros visible to ALL waves

    // ========== SQUARED distance keys (split: ~4.5/lane) + round-1 hist ======
    u32 key[NK];
    const bool kv4 = (tid < MM - 4*NTH);   // tid < 256
    {
        #pragma unroll
        for (int j = 0; j < NK; ++j) {
            key[j] = 0xFFFFFFFFu;
            if ((j < 4) || kv4) {
                int e = tid + j*NTH;
                int m = e/M, n = e - (e/M)*M;
                float dot = s_tsel[m*6+4]*s_tsel[n*6+4] + s_tsel[m*6+5]*s_tsel[n*6+5];
                float v = s_d1[m*3+2] + s_d1[n*3+2] - 2.0f*dot;
                key[j] = __float_as_uint(fmaxf(v, 0.0f));  // nonneg: uint order == float order
                atomicAdd(&s_hist[0][key[j] >> 24], 1u);
            }
        }
    }

    // ========== exact order stat 345: 4-round radix over split keys ==========
    int target = 345;
    u32 prefix = 0u, pmask = 0u;
    #pragma unroll 1
    for (int r = 0; r < 4; ++r) {
        const int shift = 24 - 8*r;
        if (r) {
            #pragma unroll
            for (int j = 0; j < NK; ++j) {
                if (((j < 4) || kv4) && (key[j] & pmask) == prefix)
                    atomicAdd(&s_hist[r][(key[j] >> shift) & 255u], 1u);
            }
        }
        WGSYNC();   // own atomics drained; all partials visible
        uint4 hv = ((const uint4*)&s_hist[r][0])[lane];
        u32 s4 = hv.x + hv.y + hv.z + hv.w;
        u32 cum = s4;
        #pragma unroll
        for (int off = 1; off < 64; off <<= 1) {
            u32 u = __shfl_up(cum, off);
            if (lane >= off) cum += u;
        }
        u64 bmask = __ballot(cum > (u32)target);
        int g = __builtin_ctzll(bmask);
        int dig = 0; u32 binstart = 0;
        if (lane == g) {
            u32 exc = cum - s4;
            int bi2 = lane*4;
            if (exc + hv.x > (u32)target)      { dig = bi2;   binstart = exc; }
            else { exc += hv.x;
                if (exc + hv.y > (u32)target)  { dig = bi2+1; binstart = exc; }
                else { exc += hv.y;
                    if (exc + hv.z > (u32)target) { dig = bi2+2; binstart = exc; }
                    else { exc += hv.z;            dig = bi2+3; binstart = exc; } } }
        }
        dig = __shfl(dig, g);
        binstart = (u32)__shfl((int)binstart, g);
        target -= (int)binstart;
        prefix |= ((u32)dig) << shift;
        pmask  |= (255u << shift);
    }
    const u32 k1 = prefix;                 // squared order stat 345
    const float v1f = sqrtf(__uint_as_float(k1));

    // ========== order stat 346: split partials + 1-barrier combine ==========
    {
        u32 cnt = 0, mng = 0xFFFFFFFFu;
        #pragma unroll
        for (int j = 0; j < NK; ++j) {     // invalid keys are 0xFFFFFFFF: no-ops
            if (key[j] <= k1) cnt++;
            else mng = (key[j] < mng) ? key[j] : mng;
        }
        #pragma unroll
        for (int off = 32; off > 0; off >>= 1) {
            cnt += __shfl_down(cnt, off);
            u32 mo = (u32)__shfl_down((int)mng, off);
            mng = (mo < mng) ? mo : mng;
        }
        if (lane == 0) { s_statc[wv] = cnt; s_statm[wv] = mng; }
    }
    WGSYNC();
    float v2f;
    {
        u32 ct = 0, mt = 0xFFFFFFFFu;
        #pragma unroll
        for (int w = 0; w < 8; ++w) {
            ct += s_statc[w];
            u32 x = s_statm[w];
            mt = (x < mt) ? x : mt;
        }
        v2f = (ct >= 347u) ? v1f : sqrtf(__uint_as_float(mt));
    }
    const float qi = 0.15f * 2303.0f;
    const float fr = qi - floorf(qi);
    const float thr = v1f*(1.0f - fr) + v2f*fr;

    // exact squared threshold: dthr = max{u : fl(sqrt(u)) <= thr}
    float dthr;
    {
        u32 ub = __float_as_uint(thr*thr);
        while (sqrtf(__uint_as_float(ub)) > thr) --ub;        // <=2 iters
        while (sqrtf(__uint_as_float(ub+1u)) <= thr) ++ub;    // <=2 iters
        dthr = __uint_as_float(ub);
    }

    // ========== adjacency, squared-space (split: ~4.5/lane) ==========
    #pragma unroll
    for (int j = 0; j < NK; ++j) {
        if ((j < 4) || kv4) {
            int e = tid + j*NTH;
            int m = e/M, n = e - (e/M)*M;
            float d0 = s_tsel[m*6+0]*s_tsel[n*6+0] + s_tsel[m*6+1]*s_tsel[n*6+1];
            float v0 = fmaxf(s_d1[m*3+0] + s_d1[n*3+0] - 2.0f*d0, 0.0f);
            float d1v = s_tsel[m*6+2]*s_tsel[n*6+2] + s_tsel[m*6+3]*s_tsel[n*6+3];
            float v1 = fmaxf(s_d1[m*3+1] + s_d1[n*3+1] - 2.0f*d1v, 0.0f);
            bool a = (__uint_as_float(key[j]) <= dthr) && (v0 <= dthr) && (v1 <= dthr);
            s_adj[e] = a ? 1.0f : 0.0f;
        }
    }
    WGSYNC();

    // ========== greedy selection + EM init: WAVE 0 ONLY ==========
    if (wv == 0) {
        const int m = (lane < M) ? lane : (M-1);
        float base = 0.f;
        #pragma unroll
        for (int n = 0; n < M; ++n) base += s_adj[n*M+m] * s_probas[n];
        float worked = 1.f;
        #pragma unroll 1
        for (int k = 0; k < NF; ++k) {
            float sc = (lane < M) ? base*worked : -1.f;
            int bi = lane;
            #pragma unroll
            for (int off = 32; off; off >>= 1) {
                float so = __shfl_down(sc, off);
                int io = __shfl_down(bi, off);
                if (so > sc || (so == sc && io < bi)) { sc = so; bi = io; }
            }
            int amax = __shfl(bi, 0);   // first-max == jnp.argmax
            if (lane == 0) s_idx[k] = amax;
            worked *= (1.f - s_adj[amax*M+m]);
        }
        // EM init -> buffer 0 (own-wave s_idx writes: in-order visible)
        if (lane < NF) {
            float mx6 = -1e30f;
            #pragma unroll
            for (int j = 0; j < NF; ++j) mx6 = fmaxf(mx6, s_logits[s_idx[j]]);
            float sum6 = 0.f;
            #pragma unroll
            for (int j = 0; j < NF; ++j) sum6 += __expf(s_logits[s_idx[j]] - mx6);
            s_probas6[0][lane] = __expf(s_logits[s_idx[lane]] - mx6) / sum6;
        }
        if (lane < NF*3) {
            int n = lane/3, tt = lane - (lane/3)*3;
            int m0 = s_idx[n];
            s_t6sel[0][n*6+tt*2+0] = s_tsel[m0*6+tt*2+0];
            s_t6sel[0][n*6+tt*2+1] = s_tsel[m0*6+tt*2+1];
            float c00 = s_csel[(m0*3+tt)*4+0];
            float c01 = s_csel[(m0*3+tt)*4+1];
            float c11 = s_csel[(m0*3+tt)*4+2];
            float det = c00*c11 - c01*c01;
            float rdet = __fdividef(1.0f, det);
            s_prec[0][lane*3+0] =  c11*rdet;
            s_prec[0][lane*3+1] = -c01*rdet;
            s_prec[0][lane*3+2] =  c00*rdet;
            s_ld[0][lane] = __logf(det);
        }
    }
    WGSYNC();   // state[0] + s_idx visible to all waves

    // ========== EM loop: SPLIT E-step (384 lanes) + SPLIT selector M-step ====
    // E-step mapping: mE = tid>>3 (row, <48), nE = tid&7 (component, <6).
    const int mE = tid >> 3;           // 0..63
    const int nE = tid & 7;            // 0..7
    const bool eAct = (mE < M) && (nE < NF);
    const int eSlot = (nE < 3) ? nE : nE + 1;
    float tmE0=0.f,tmE1=0.f,tmE2=0.f,tmE3=0.f,tmE4=0.f,tmE5=0.f,probaE=0.f;
    if (mE < M) {
        tmE0=s_tsel[mE*6+0]; tmE1=s_tsel[mE*6+1]; tmE2=s_tsel[mE*6+2];
        tmE3=s_tsel[mE*6+3]; tmE4=s_tsel[mE*6+4]; tmE5=s_tsel[mE*6+5];
        probaE = s_probas[mE];
    }
    const int gid = tid >> 3;          // 8-lane group id (18 active, waves 0-2)
    const int sub = tid & 7;
    const int gn  = gid/3, gtt = gid - (gid/3)*3;      // valid when gid<18
    const int gslot = (gn < 3) ? gn : gn + 1;

    #pragma unroll 1
    for (int it = 0; it < EMIT; ++it) {
        const int cur = it & 1, nxt = cur ^ 1;
        const float* prC = s_prec[cur];
        const float* ldC = s_ld[cur];
        const float* t6C = s_t6sel[cur];
        const float* p6C = s_probas6[cur];

        // ---- E-step: one component per lane, 19 broadcast LDS reads ----
        float numv = 0.f;
        if (eAct) {
            const float* prn = prC + nE*9;
            float lsum = ldC[nE*3+0] + ldC[nE*3+1] + ldC[nE*3+2];
            float dx0 = t6C[nE*6+0]-tmE0, dy0 = t6C[nE*6+1]-tmE1;
            float dx1 = t6C[nE*6+2]-tmE2, dy1 = t6C[nE*6+3]-tmE3;
            float dx2 = t6C[nE*6+4]-tmE4, dy2 = t6C[nE*6+5]-tmE5;
            float q = prn[0]*dx0*dx0 + 2.f*prn[1]*dx0*dy0 + prn[2]*dy0*dy0
                    + prn[3]*dx1*dx1 + 2.f*prn[4]*dx1*dy1 + prn[5]*dy1*dy1
                    + prn[6]*dx2*dx2 + 2.f*prn[7]*dx2*dy2 + prn[8]*dy2*dy2;
            numv = (__expf(-3.f*LOG2PI - 0.5f*lsum - 0.5f*q) + 1e-8f) * p6C[nE];
        }
        float den = numv;                    // group-of-8 sum (lanes 6,7 = 0)
        den += __shfl_xor(den, 1);
        den += __shfl_xor(den, 2);
        den += __shfl_xor(den, 4);
        den += 1e-8f;
        if (eAct) s_Pm[mE*8 + eSlot] = numv * __fdividef(probaE, den);
        if (it == EMIT-1) break;

        WGSYNC();   // s_Pm (cross-wave) visible to M-step groups

        // ---- selector M-step SPLIT: 18 items x 8-lane groups, 6-deep loops ----
        if (gid < 18) {
            float SP=0,S1x=0,S1y=0,Sxx=0,Sxy=0,Syy=0,C0=0,C1=0,C2=0;
            #pragma unroll
            for (int k = 0; k < 6; ++k) {
                int mm = sub*6 + k;
                float p = s_Pm[mm*8 + gslot];
                float x = s_tsel[mm*6+gtt*2+0];
                float y = s_tsel[mm*6+gtt*2+1];
                float4 c4 = *(const float4*)&s_csel[(mm*3+gtt)*4];
                SP += p; S1x += p*x; S1y += p*y;
                Sxx += p*x*x; Sxy += p*x*y; Syy += p*y*y;
                C0 += p*c4.x; C1 += p*c4.y; C2 += p*c4.z;
            }
            #define R8(v) { v += __shfl_down(v,4); v += __shfl_down(v,2); v += __shfl_down(v,1); }
            R8(SP) R8(S1x) R8(S1y) R8(Sxx) R8(Sxy) R8(Syy) R8(C0) R8(C1) R8(C2)
            #undef R8
            if (sub == 0) {
                float p6 = SP;
                float tx = __fdividef(S1x, p6), ty = __fdividef(S1y, p6);
                float rp = __fdividef(1.0f, p6);
                float c00 = (C0 + (Sxx - S1x*tx)) * rp;
                float c01 = (C1 + (Sxy - S1x*ty)) * rp;
                float c11 = (C2 + (Syy - S1y*ty)) * rp;
                float det = c00*c11 - c01*c01;
                float rdet = __fdividef(1.0f, det);
                s_prec[nxt][gid*3+0] =  c11*rdet;
                s_prec[nxt][gid*3+1] = -c01*rdet;
                s_prec[nxt][gid*3+2] =  c00*rdet;
                s_ld[nxt][gid] = __logf(det);
                s_t6sel[nxt][gn*6+gtt*2+0] = tx;
                s_t6sel[nxt][gn*6+gtt*2+1] = ty;
                if (gtt == 0) s_probas6[nxt][gn] = SP;
            }
        }
        WGSYNC();   // state[nxt] visible; DMA (vmcnt) stays in flight
    }

    // ========== full sync: DMA + last E-step visible ==========
    WGSYNC_ALL();

    // ========== final full-T M-step: 240 items x 2 lanes (24-deep loops) =====
    float*  out_p = g_out;
    float2* out_t = (float2*)(g_out + BATCH*NF);
    float4* out_c = (float4*)(g_out + BATCH*NF + BATCH*NF*T*2);
    if (lane < 60) {
        int item = wv*30 + (lane >> 1);   // 0..239 = (t, third)
        int half = lane & 1;              // mm range split across lane pair
        int t = item/3, third = item - (item/3)*3;
        int nA = third*2, nB = nA + 1;
        int slotA = (nA < 3) ? nA : nA + 1;
        int slotB = (nB < 3) ? nB : nB + 1;
        float SPa=0,S1xa=0,S1ya=0,Sxxa=0,Sxya=0,Syya=0,C00a=0,C01a=0,C11a=0;
        float SPb=0,S1xb=0,S1yb=0,Sxxb=0,Sxyb=0,Syyb=0,C00b=0,C01b=0,C11b=0;
        const int m0 = half*24;
        #pragma unroll 4
        for (int k = 0; k < 24; ++k) {
            int mm = m0 + k;
            float2 xy = ((const float2*)s_txy)[mm*T + t];
            float4 c4 = ((const float4*)s_cv4)[mm*T + t];
            float pa = s_Pm[mm*8 + slotA];
            float pb = s_Pm[mm*8 + slotB];
            float xx = xy.x*xy.x, xyv = xy.x*xy.y, yy = xy.y*xy.y;
            SPa+=pa; S1xa+=pa*xy.x; S1ya+=pa*xy.y;
            Sxxa+=pa*xx; Sxya+=pa*xyv; Syya+=pa*yy;
            C00a+=pa*c4.x; C01a+=pa*c4.y; C11a+=pa*c4.w;
            SPb+=pb; S1xb+=pb*xy.x; S1yb+=pb*xy.y;
            Sxxb+=pb*xx; Sxyb+=pb*xyv; Syyb+=pb*yy;
            C00b+=pb*c4.x; C01b+=pb*c4.y; C11b+=pb*c4.w;
        }
        // combine lane pair: both lanes end with full sums
        #define CX(v) v += __shfl_xor(v, 1);
        CX(SPa) CX(S1xa) CX(S1ya) CX(Sxxa) CX(Sxya) CX(Syya) CX(C00a) CX(C01a) CX(C11a)
        CX(SPb) CX(S1xb) CX(S1yb) CX(Sxxb) CX(Sxyb) CX(Syyb) CX(C00b) CX(C01b) CX(C11b)
        #undef CX
        if (half == 0) {
            float p6 = SPa;
            float tx = __fdividef(S1xa, p6), ty = __fdividef(S1ya, p6);
            float rp = __fdividef(1.0f, p6);
            float c00 = (C00a + (Sxxa - S1xa*tx)) * rp;
            float c01 = (C01a + (Sxya - S1xa*ty)) * rp;
            float c11 = (C11a + (Syya - S1ya*ty)) * rp;
            size_t o = (size_t)(b*NF + nA)*T + t;
            out_t[o] = make_float2(tx, ty);
            out_c[o] = make_float4(c00, c01, c01, c11);
        } else {
            float p6 = SPb;
            float tx = __fdividef(S1xb, p6), ty = __fdividef(S1yb, p6);
            float rp = __fdividef(1.0f, p6);
            float c00 = (C00b + (Sxxb - S1xb*tx)) * rp;
            float c01 = (C01b + (Sxyb - S1xb*ty)) * rp;
            float c11 = (C11b + (Syyb - S1yb*ty)) * rp;
            size_t o = (size_t)(b*NF + nB)*T + t;
            out_t[o] = make_float2(tx, ty);
            out_c[o] = make_float4(c00, c01, c01, c11);
        }
    }
    if (wv == 0 && lane < NF) {
        int slot = (lane < 3) ? lane : lane + 1;
        float sp = 0.f;
        for (int mm = 0; mm < M; ++mm) sp += s_Pm[mm*8 + slot];
        out_p[b*NF + lane] = sp;
    }
}

extern "C" void kernel_launch(void* const* d_in, const int* in_sizes, int n_in,
                              void* d_out, int out_size, void* d_ws, size_t ws_size,
                              hipStream_t stream) {
    const float* logits = (const float*)d_in[0];
    const float* traj   = (const float*)d_in[1];
    const float* cov    = (const float*)d_in[2];
    float* out = (float*)d_out;
    em_kernel<<<dim3(BATCH), dim3(NTH), 0, stream>>>(logits, traj, cov, out);
}

// Round 4
// 98.688 us; speedup vs baseline: 1.0177x; 1.0177x over previous
//
#include <hip/hip_runtime.h>
#include <math.h>

#define BATCH 256
#define M 48
#define T 80
#define NF 6
#define EMIT 10
#define MM (M*M)        // 2304
#define NTH 512         // 8 waves/block -> 2 waves/SIMD
#define NK 5            // ceil(2304/512); 5th key valid only for tid<256
#define PMW 52          // padded row stride of transposed P (bank spread)
#define LOG2PI 1.8378770664093453f

typedef unsigned int u32;
typedef unsigned long long u64;

// Raw workgroup sync: drains LDS (lgkm) only -- async global_load_lds DMA
// (vmcnt) stays in flight. "memory" clobber stops compiler caching LDS in regs.
#define WGSYNC()     __asm__ __volatile__("s_waitcnt lgkmcnt(0)\ns_barrier" ::: "memory")
#define WGSYNC_ALL() __asm__ __volatile__("s_waitcnt vmcnt(0) lgkmcnt(0)\ns_barrier" ::: "memory")

// 8 waves/block. EM-LOOP DIET this round (arithmetic identical):
//  (1) E-step state arrays padded to 16B-aligned strides (prec 16, t6 8, ld 4)
//      -> 7 vector LDS reads/lane instead of 19 scalars.
//  (2) M-step loop-invariant s_tsel/s_csel values hoisted to registers ONCE
//      (loaded during wave-0's greedy phase) -> per-iter M reads = P only.
//  (3) P stored TRANSPOSED s_PmT[n][52] -> M-step reads 6 consecutive P as
//      3x b64; 52-stride spreads banks for E-write/final-read.
// Per-iter LDS wave-instrs ~235 -> ~95; 2 lgkm-only barriers/iter unchanged.
__global__ __launch_bounds__(NTH, 1)
void em_kernel(const float* __restrict__ g_logits,
               const float* __restrict__ g_traj,
               const float* __restrict__ g_cov,
               float* __restrict__ g_out)
{
    const int b = blockIdx.x;
    const int tid = threadIdx.x;
    const int lane = tid & 63;
    const int wv = tid >> 6;          // 0..7
    const int SEL[3] = {29, 49, 79};

    // ---- LDS ~110 KB ----
    __shared__ __align__(16) float s_txy[M*T*2];   // staged traj (DMA)
    __shared__ __align__(16) float s_cv4[M*T*4];   // staged cov (DMA)
    __shared__ float s_adj[MM];
    __shared__ float s_logits[M];
    __shared__ float s_probas[M];
    __shared__ float s_tsel[M*6];                  // [m][tt][d]
    __shared__ float s_d1[M*3];
    __shared__ __align__(16) float s_csel[M*3*4];  // [m][tt]{c00,c01,c11,pad}
    __shared__ __align__(16) float s_PmT[NF*PMW];  // TRANSPOSED P: [n][m], stride 52
    __shared__ __align__(16) float s_t6sel[2][NF*8];   // ping-pong, stride 8/comp
    __shared__ float s_probas6[2][NF];
    __shared__ __align__(16) float s_prec[2][NF*16];   // stride 16/comp (9 used)
    __shared__ __align__(16) float s_ld[2][NF*4];      // stride 4/comp (3 used)
    __shared__ int   s_idx[8];
    __shared__ __align__(16) u32 s_hist[4][256];   // shared per-round hists
    __shared__ u32 s_statc[8], s_statm[8];

    const float* traj_b = g_traj + (size_t)b*(M*T*2);
    const float* cov_b  = g_cov  + (size_t)b*(M*T*4);

    // ========== direct gathers FIRST (redundant per wave; oldest vmem ops) ====
    float myLogit = -1e30f;
    if (lane < M) myLogit = g_logits[b*M + lane];
    float selx[3], sely[3], cc0[3], cc1[3], cc2[3];
    #pragma unroll
    for (int r = 0; r < 3; ++r) {
        int i = lane + r*64;
        if (i < M*3) {
            int m = i/3, tt = i - (i/3)*3;
            float2 xy = ((const float2*)traj_b)[m*T + SEL[tt]];
            float4 cv = ((const float4*)cov_b)[m*T + SEL[tt]];
            selx[r]=xy.x; sely[r]=xy.y; cc0[r]=cv.x; cc1[r]=cv.y; cc2[r]=cv.w;
        }
    }

    // ========== DMA staging AFTER gathers, split 8 ways ==========
    __builtin_amdgcn_sched_barrier(0);
    {
        const char* gt = (const char*)traj_b + lane*16;
        char* lt = (char*)s_txy;
        #pragma unroll 2
        for (int k = wv; k < 30; k += 8)
            __builtin_amdgcn_global_load_lds(
                (const __attribute__((address_space(1))) u32*)(gt + k*1024),
                (__attribute__((address_space(3))) u32*)(lt + k*1024), 16, 0, 0);
        const char* gc = (const char*)cov_b + lane*16;
        char* lc = (char*)s_cv4;
        #pragma unroll 2
        for (int k = wv; k < 60; k += 8)
            __builtin_amdgcn_global_load_lds(
                (const __attribute__((address_space(1))) u32*)(gc + k*1024),
                (__attribute__((address_space(3))) u32*)(lc + k*1024), 16, 0, 0);
    }
    __builtin_amdgcn_sched_barrier(0);

    // ========== zero shared hists ==========
    if (tid < 256) ((uint4*)s_hist)[tid] = make_uint4(0,0,0,0);

    // ========== stage selector data (redundant identical writes) ==========
    if (lane < M) s_logits[lane] = myLogit;
    #pragma unroll
    for (int r = 0; r < 3; ++r) {
        int i = lane + r*64;
        if (i < M*3) {
            int m = i/3, tt = i - (i/3)*3;
            s_tsel[m*6+tt*2+0] = selx[r];
            s_tsel[m*6+tt*2+1] = sely[r];
            s_d1[i] = selx[r]*selx[r] + sely[r]*sely[r];
            s_csel[i*4+0]=cc0[r]; s_csel[i*4+1]=cc1[r]; s_csel[i*4+2]=cc2[r]; s_csel[i*4+3]=0.f;
        }
    }

    // ========== softmax (in-wave, registers; redundant per wave) ==========
    float mx = myLogit;
    #pragma unroll
    for (int off = 32; off; off >>= 1) mx = fmaxf(mx, __shfl_xor(mx, off));
    float pe = (lane < M) ? __expf(myLogit - mx) : 0.f;
    float psum = pe;
    #pragma unroll
    for (int off = 32; off; off >>= 1) psum += __shfl_xor(psum, off);
    if (lane < M) s_probas[lane] = pe / psum;

    WGSYNC();   // staging + softmax + hist zeros visible to ALL waves

    // ========== SQUARED distance keys (split: ~4.5/lane) + round-1 hist ======
    u32 key[NK];
    const bool kv4 = (tid < MM - 4*NTH);   // tid < 256
    {
        #pragma unroll
        for (int j = 0; j < NK; ++j) {
            key[j] = 0xFFFFFFFFu;
            if ((j < 4) || kv4) {
                int e = tid + j*NTH;
                int m = e/M, n = e - (e/M)*M;
                float dot = s_tsel[m*6+4]*s_tsel[n*6+4] + s_tsel[m*6+5]*s_tsel[n*6+5];
                float v = s_d1[m*3+2] + s_d1[n*3+2] - 2.0f*dot;
                key[j] = __float_as_uint(fmaxf(v, 0.0f));  // nonneg: uint order == float order
                atomicAdd(&s_hist[0][key[j] >> 24], 1u);
            }
        }
    }

    // ========== exact order stat 345: 4-round radix over split keys ==========
    int target = 345;
    u32 prefix = 0u, pmask = 0u;
    #pragma unroll 1
    for (int r = 0; r < 4; ++r) {
        const int shift = 24 - 8*r;
        if (r) {
            #pragma unroll
            for (int j = 0; j < NK; ++j) {
                if (((j < 4) || kv4) && (key[j] & pmask) == prefix)
                    atomicAdd(&s_hist[r][(key[j] >> shift) & 255u], 1u);
            }
        }
        WGSYNC();   // own atomics drained; all partials visible
        uint4 hv = ((const uint4*)&s_hist[r][0])[lane];
        u32 s4 = hv.x + hv.y + hv.z + hv.w;
        u32 cum = s4;
        #pragma unroll
        for (int off = 1; off < 64; off <<= 1) {
            u32 u = __shfl_up(cum, off);
            if (lane >= off) cum += u;
        }
        u64 bmask = __ballot(cum > (u32)target);
        int g = __builtin_ctzll(bmask);
        int dig = 0; u32 binstart = 0;
        if (lane == g) {
            u32 exc = cum - s4;
            int bi2 = lane*4;
            if (exc + hv.x > (u32)target)      { dig = bi2;   binstart = exc; }
            else { exc += hv.x;
                if (exc + hv.y > (u32)target)  { dig = bi2+1; binstart = exc; }
                else { exc += hv.y;
                    if (exc + hv.z > (u32)target) { dig = bi2+2; binstart = exc; }
                    else { exc += hv.z;            dig = bi2+3; binstart = exc; } } }
        }
        dig = __shfl(dig, g);
        binstart = (u32)__shfl((int)binstart, g);
        target -= (int)binstart;
        prefix |= ((u32)dig) << shift;
        pmask  |= (255u << shift);
    }
    const u32 k1 = prefix;                 // squared order stat 345
    const float v1f = sqrtf(__uint_as_float(k1));

    // ========== order stat 346: split partials + 1-barrier combine ==========
    {
        u32 cnt = 0, mng = 0xFFFFFFFFu;
        #pragma unroll
        for (int j = 0; j < NK; ++j) {     // invalid keys are 0xFFFFFFFF: no-ops
            if (key[j] <= k1) cnt++;
            else mng = (key[j] < mng) ? key[j] : mng;
        }
        #pragma unroll
        for (int off = 32; off > 0; off >>= 1) {
            cnt += __shfl_down(cnt, off);
            u32 mo = (u32)__shfl_down((int)mng, off);
            mng = (mo < mng) ? mo : mng;
        }
        if (lane == 0) { s_statc[wv] = cnt; s_statm[wv] = mng; }
    }
    WGSYNC();
    float v2f;
    {
        u32 ct = 0, mt = 0xFFFFFFFFu;
        #pragma unroll
        for (int w = 0; w < 8; ++w) {
            ct += s_statc[w];
            u32 x = s_statm[w];
            mt = (x < mt) ? x : mt;
        }
        v2f = (ct >= 347u) ? v1f : sqrtf(__uint_as_float(mt));
    }
    const float qi = 0.15f * 2303.0f;
    const float fr = qi - floorf(qi);
    const float thr = v1f*(1.0f - fr) + v2f*fr;

    // exact squared threshold: dthr = max{u : fl(sqrt(u)) <= thr}
    float dthr;
    {
        u32 ub = __float_as_uint(thr*thr);
        while (sqrtf(__uint_as_float(ub)) > thr) --ub;        // <=2 iters
        while (sqrtf(__uint_as_float(ub+1u)) <= thr) ++ub;    // <=2 iters
        dthr = __uint_as_float(ub);
    }

    // ========== adjacency, squared-space (split: ~4.5/lane) ==========
    #pragma unroll
    for (int j = 0; j < NK; ++j) {
        if ((j < 4) || kv4) {
            int e = tid + j*NTH;
            int m = e/M, n = e - (e/M)*M;
            float d0 = s_tsel[m*6+0]*s_tsel[n*6+0] + s_tsel[m*6+1]*s_tsel[n*6+1];
            float v0 = fmaxf(s_d1[m*3+0] + s_d1[n*3+0] - 2.0f*d0, 0.0f);
            float d1v = s_tsel[m*6+2]*s_tsel[n*6+2] + s_tsel[m*6+3]*s_tsel[n*6+3];
            float v1 = fmaxf(s_d1[m*3+1] + s_d1[n*3+1] - 2.0f*d1v, 0.0f);
            bool a = (__uint_as_float(key[j]) <= dthr) && (v0 <= dthr) && (v1 <= dthr);
            s_adj[e] = a ? 1.0f : 0.0f;
        }
    }
    WGSYNC();

    // ========== EM lane roles + loop-invariant register preloads ==========
    // (runs on waves 1-7 while wave 0 does greedy below -- free)
    const int mE = tid >> 3;           // 0..63 (E-step row)
    const int nE = tid & 7;            // 0..7  (E-step component)
    const bool eAct = (mE < M) && (nE < NF);
    const int gid = tid >> 3;          // M-step group id (18 active)
    const int sub = tid & 7;
    const int gn  = gid/3, gtt = gid - (gid/3)*3;      // valid when gid<18
    float tmE0=0.f,tmE1=0.f,tmE2=0.f,tmE3=0.f,tmE4=0.f,tmE5=0.f,probaE=0.f;
    if (mE < M) {
        float2 a0 = *(const float2*)&s_tsel[mE*6+0];
        float2 a1 = *(const float2*)&s_tsel[mE*6+2];
        float2 a2 = *(const float2*)&s_tsel[mE*6+4];
        tmE0=a0.x; tmE1=a0.y; tmE2=a1.x; tmE3=a1.y; tmE4=a2.x; tmE5=a2.y;
        probaE = s_probas[mE];
    }
    float Mx[6], My[6], Mc0[6], Mc1[6], Mc2[6];
    if (gid < 18) {
        #pragma unroll
        for (int k = 0; k < 6; ++k) {
            int mm = sub*6 + k;
            float2 xy = *(const float2*)&s_tsel[mm*6+gtt*2];
            float4 c4 = *(const float4*)&s_csel[(mm*3+gtt)*4];
            Mx[k]=xy.x; My[k]=xy.y; Mc0[k]=c4.x; Mc1[k]=c4.y; Mc2[k]=c4.z;
        }
    }

    // ========== greedy selection + EM init: WAVE 0 ONLY ==========
    if (wv == 0) {
        const int m = (lane < M) ? lane : (M-1);
        float base = 0.f;
        #pragma unroll
        for (int n = 0; n < M; ++n) base += s_adj[n*M+m] * s_probas[n];
        float worked = 1.f;
        #pragma unroll 1
        for (int k = 0; k < NF; ++k) {
            float sc = (lane < M) ? base*worked : -1.f;
            int bi = lane;
            #pragma unroll
            for (int off = 32; off; off >>= 1) {
                float so = __shfl_down(sc, off);
                int io = __shfl_down(bi, off);
                if (so > sc || (so == sc && io < bi)) { sc = so; bi = io; }
            }
            int amax = __shfl(bi, 0);   // first-max == jnp.argmax
            if (lane == 0) s_idx[k] = amax;
            worked *= (1.f - s_adj[amax*M+m]);
        }
        // EM init -> buffer 0 (own-wave s_idx writes: in-order visible)
        if (lane < NF) {
            float mx6 = -1e30f;
            #pragma unroll
            for (int j = 0; j < NF; ++j) mx6 = fmaxf(mx6, s_logits[s_idx[j]]);
            float sum6 = 0.f;
            #pragma unroll
            for (int j = 0; j < NF; ++j) sum6 += __expf(s_logits[s_idx[j]] - mx6);
            s_probas6[0][lane] = __expf(s_logits[s_idx[lane]] - mx6) / sum6;
        }
        if (lane < NF*3) {
            int n = lane/3, tt = lane - (lane/3)*3;
            int m0 = s_idx[n];
            s_t6sel[0][n*8+tt*2+0] = s_tsel[m0*6+tt*2+0];
            s_t6sel[0][n*8+tt*2+1] = s_tsel[m0*6+tt*2+1];
            float c00 = s_csel[(m0*3+tt)*4+0];
            float c01 = s_csel[(m0*3+tt)*4+1];
            float c11 = s_csel[(m0*3+tt)*4+2];
            float det = c00*c11 - c01*c01;
            float rdet = __fdividef(1.0f, det);
            s_prec[0][n*16+tt*3+0] =  c11*rdet;
            s_prec[0][n*16+tt*3+1] = -c01*rdet;
            s_prec[0][n*16+tt*3+2] =  c00*rdet;
            s_ld[0][n*4+tt] = __logf(det);
        }
    }
    WGSYNC();   // state[0] + s_idx visible to all waves

    // ========== EM loop: vectorized E-step + register-hoisted M-step ==========
    #pragma unroll 1
    for (int it = 0; it < EMIT; ++it) {
        const int cur = it & 1, nxt = cur ^ 1;

        // ---- E-step: one component per lane, 7 vector LDS reads ----
        float numv = 0.f;
        if (eAct) {
            const float* prB = &s_prec[cur][nE*16];
            float4 pr0 = *(const float4*)(prB);
            float4 pr1 = *(const float4*)(prB+4);
            float  pr8 = prB[8];
            float4 t60 = *(const float4*)&s_t6sel[cur][nE*8];
            float2 t62 = *(const float2*)&s_t6sel[cur][nE*8+4];
            float4 ldv = *(const float4*)&s_ld[cur][nE*4];
            float  p6v = s_probas6[cur][nE];
            float lsum = ldv.x + ldv.y + ldv.z;
            float dx0 = t60.x-tmE0, dy0 = t60.y-tmE1;
            float dx1 = t60.z-tmE2, dy1 = t60.w-tmE3;
            float dx2 = t62.x-tmE4, dy2 = t62.y-tmE5;
            float q = pr0.x*dx0*dx0 + 2.f*pr0.y*dx0*dy0 + pr0.z*dy0*dy0
                    + pr0.w*dx1*dx1 + 2.f*pr1.x*dx1*dy1 + pr1.y*dy1*dy1
                    + pr1.z*dx2*dx2 + 2.f*pr1.w*dx2*dy2 + pr8*dy2*dy2;
            numv = (__expf(-3.f*LOG2PI - 0.5f*lsum - 0.5f*q) + 1e-8f) * p6v;
        }
        float den = numv;                    // group-of-8 sum (lanes 6,7 = 0)
        den += __shfl_xor(den, 1);
        den += __shfl_xor(den, 2);
        den += __shfl_xor(den, 4);
        den += 1e-8f;
        if (eAct) s_PmT[nE*PMW + mE] = numv * __fdividef(probaE, den);
        if (it == EMIT-1) break;

        WGSYNC();   // s_PmT (cross-wave) visible to M-step groups

        // ---- selector M-step: P-only LDS reads (3x b64), hoisted constants ----
        if (gid < 18) {
            const float* pB = &s_PmT[gn*PMW + sub*6];
            float2 p01 = *(const float2*)(pB);
            float2 p23 = *(const float2*)(pB+2);
            float2 p45 = *(const float2*)(pB+4);
            float pv[6] = {p01.x, p01.y, p23.x, p23.y, p45.x, p45.y};
            float SP=0,S1x=0,S1y=0,Sxx=0,Sxy=0,Syy=0,C0=0,C1=0,C2=0;
            #pragma unroll
            for (int k = 0; k < 6; ++k) {
                float p = pv[k];
                float x = Mx[k], y = My[k];
                SP += p; S1x += p*x; S1y += p*y;
                Sxx += p*x*x; Sxy += p*x*y; Syy += p*y*y;
                C0 += p*Mc0[k]; C1 += p*Mc1[k]; C2 += p*Mc2[k];
            }
            #define R8(v) { v += __shfl_down(v,4); v += __shfl_down(v,2); v += __shfl_down(v,1); }
            R8(SP) R8(S1x) R8(S1y) R8(Sxx) R8(Sxy) R8(Syy) R8(C0) R8(C1) R8(C2)
            #undef R8
            if (sub == 0) {
                float p6 = SP;
                float tx = __fdividef(S1x, p6), ty = __fdividef(S1y, p6);
                float rp = __fdividef(1.0f, p6);
                float c00 = (C0 + (Sxx - S1x*tx)) * rp;
                float c01 = (C1 + (Sxy - S1x*ty)) * rp;
                float c11 = (C2 + (Syy - S1y*ty)) * rp;
                float det = c00*c11 - c01*c01;
                float rdet = __fdividef(1.0f, det);
                s_prec[nxt][gn*16+gtt*3+0] =  c11*rdet;
                s_prec[nxt][gn*16+gtt*3+1] = -c01*rdet;
                s_prec[nxt][gn*16+gtt*3+2] =  c00*rdet;
                s_ld[nxt][gn*4+gtt] = __logf(det);
                s_t6sel[nxt][gn*8+gtt*2+0] = tx;
                s_t6sel[nxt][gn*8+gtt*2+1] = ty;
                if (gtt == 0) s_probas6[nxt][gn] = SP;
            }
        }
        WGSYNC();   // state[nxt] visible; DMA (vmcnt) stays in flight
    }

    // ========== full sync: DMA + last E-step visible ==========
    WGSYNC_ALL();

    // ========== final full-T M-step: 240 items x 2 lanes (24-deep loops) =====
    float*  out_p = g_out;
    float2* out_t = (float2*)(g_out + BATCH*NF);
    float4* out_c = (float4*)(g_out + BATCH*NF + BATCH*NF*T*2);
    if (lane < 60) {
        int item = wv*30 + (lane >> 1);   // 0..239 = (t, third)
        int half = lane & 1;              // mm range split across lane pair
        int t = item/3, third = item - (item/3)*3;
        int nA = third*2, nB = nA + 1;
        float SPa=0,S1xa=0,S1ya=0,Sxxa=0,Sxya=0,Syya=0,C00a=0,C01a=0,C11a=0;
        float SPb=0,S1xb=0,S1yb=0,Sxxb=0,Sxyb=0,Syyb=0,C00b=0,C01b=0,C11b=0;
        const int m0 = half*24;
        #pragma unroll 4
        for (int k = 0; k < 24; ++k) {
            int mm = m0 + k;
            float2 xy = ((const float2*)s_txy)[mm*T + t];
            float4 c4 = ((const float4*)s_cv4)[mm*T + t];
            float pa = s_PmT[nA*PMW + mm];
            float pb = s_PmT[nB*PMW + mm];
            float xx = xy.x*xy.x, xyv = xy.x*xy.y, yy = xy.y*xy.y;
            SPa+=pa; S1xa+=pa*xy.x; S1ya+=pa*xy.y;
            Sxxa+=pa*xx; Sxya+=pa*xyv; Syya+=pa*yy;
            C00a+=pa*c4.x; C01a+=pa*c4.y; C11a+=pa*c4.w;
            SPb+=pb; S1xb+=pb*xy.x; S1yb+=pb*xy.y;
            Sxxb+=pb*xx; Sxyb+=pb*xyv; Syyb+=pb*yy;
            C00b+=pb*c4.x; C01b+=pb*c4.y; C11b+=pb*c4.w;
        }
        // combine lane pair: both lanes end with full sums
        #define CX(v) v += __shfl_xor(v, 1);
        CX(SPa) CX(S1xa) CX(S1ya) CX(Sxxa) CX(Sxya) CX(Syya) CX(C00a) CX(C01a) CX(C11a)
        CX(SPb) CX(S1xb) CX(S1yb) CX(Sxxb) CX(Sxyb) CX(Syyb) CX(C00b) CX(C01b) CX(C11b)
        #undef CX
        if (half == 0) {
            float p6 = SPa;
            float tx = __fdividef(S1xa, p6), ty = __fdividef(S1ya, p6);
            float rp = __fdividef(1.0f, p6);
            float c00 = (C00a + (Sxxa - S1xa*tx)) * rp;
            float c01 = (C01a + (Sxya - S1xa*ty)) * rp;
            float c11 = (C11a + (Syya - S1ya*ty)) * rp;
            size_t o = (size_t)(b*NF + nA)*T + t;
            out_t[o] = make_float2(tx, ty);
            out_c[o] = make_float4(c00, c01, c01, c11);
        } else {
            float p6 = SPb;
            float tx = __fdividef(S1xb, p6), ty = __fdividef(S1yb, p6);
            float rp = __fdividef(1.0f, p6);
            float c00 = (C00b + (Sxxb - S1xb*tx)) * rp;
            float c01 = (C01b + (Sxyb - S1xb*ty)) * rp;
            float c11 = (C11b + (Syyb - S1yb*ty)) * rp;
            size_t o = (size_t)(b*NF + nB)*T + t;
            out_t[o] = make_float2(tx, ty);
            out_c[o] = make_float4(c00, c01, c01, c11);
        }
    }
    if (wv == 0 && lane < NF) {
        float sp = 0.f;
        #pragma unroll
        for (int j = 0; j < 24; ++j) {
            float2 v = *(const float2*)&s_PmT[lane*PMW + 2*j];
            sp += v.x; sp += v.y;
        }
        out_p[b*NF + lane] = sp;
    }
}

extern "C" void kernel_launch(void* const* d_in, const int* in_sizes, int n_in,
                              void* d_out, int out_size, void* d_ws, size_t ws_size,
                              hipStream_t stream) {
    const float* logits = (const float*)d_in[0];
    const float* traj   = (const float*)d_in[1];
    const float* cov    = (const float*)d_in[2];
    float* out = (float*)d_out;
    em_kernel<<<dim3(BATCH), dim3(NTH), 0, stream>>>(logits, traj, cov, out);
}

// Round 5
// 98.366 us; speedup vs baseline: 1.0211x; 1.0033x over previous
//
#include <hip/hip_runtime.h>
#include <math.h>

#define BATCH 256
#define M 48
#define T 80
#define NF 6
#define EMIT 10
#define MM (M*M)        // 2304
#define NTH 512         // 8 waves/block -> 2 waves/SIMD
#define NK 5            // ceil(2304/512); 5th key valid only for tid<256
#define PMW 52          // padded row stride of transposed P (bank spread)
#define H1W 264         // replica hist stride (264%32=8 -> bank-spread replicas)
#define PRW 20          // s_prec per-component stride (80B: conflict-free quads)
#define LOG2PI 1.8378770664093453f

typedef unsigned int u32;
typedef unsigned long long u64;

// Raw workgroup sync: drains LDS (lgkm) only -- async global_load_lds DMA
// (vmcnt) stays in flight. "memory" clobber stops compiler caching LDS in regs.
#define WGSYNC()     __asm__ __volatile__("s_waitcnt lgkmcnt(0)\ns_barrier" ::: "memory")
#define WGSYNC_ALL() __asm__ __volatile__("s_waitcnt vmcnt(0) lgkmcnt(0)\ns_barrier" ::: "memory")

// 8 waves/block. LDS-SERIALIZATION FIXES this round (arithmetic identical):
//  (1) Radix ROUND-1 hist is per-wave replicated s_h1[8][264]: exponent-
//      clustered keys no longer serialize cross-wave on identical addresses;
//      scan combines 8 uint4 loads. Rounds 2-4 stay shared (uncontended).
//  (2) s_prec stride 16->20 floats: E-step b128 reads hit disjoint bank
//      quads {0,20,8,28,16,4,24,12} -- was 4-way aliased at stride 16.
//  (3) Order-stat-346 tie case folded into the radix scan (#<=k1 =
//      345-target+s); the min-scan + barrier runs only in the no-tie branch
//      (block-uniform condition), and the cnt-reduction is gone.
__global__ __launch_bounds__(NTH, 1)
void em_kernel(const float* __restrict__ g_logits,
               const float* __restrict__ g_traj,
               const float* __restrict__ g_cov,
               float* __restrict__ g_out)
{
    const int b = blockIdx.x;
    const int tid = threadIdx.x;
    const int lane = tid & 63;
    const int wv = tid >> 6;          // 0..7
    const int SEL[3] = {29, 49, 79};

    // ---- LDS ~117 KB ----
    __shared__ __align__(16) float s_txy[M*T*2];   // staged traj (DMA)
    __shared__ __align__(16) float s_cv4[M*T*4];   // staged cov (DMA)
    __shared__ float s_adj[MM];
    __shared__ float s_logits[M];
    __shared__ float s_probas[M];
    __shared__ float s_tsel[M*6];                  // [m][tt][d]
    __shared__ float s_d1[M*3];
    __shared__ __align__(16) float s_csel[M*3*4];  // [m][tt]{c00,c01,c11,pad}
    __shared__ __align__(16) float s_PmT[NF*PMW];  // TRANSPOSED P: [n][m], stride 52
    __shared__ __align__(16) float s_t6sel[2][NF*8];   // ping-pong, stride 8/comp
    __shared__ float s_probas6[2][NF];
    __shared__ __align__(16) float s_prec[2][NF*PRW];  // stride 20/comp (9 used)
    __shared__ __align__(16) float s_ld[2][NF*4];      // stride 4/comp (3 used)
    __shared__ int   s_idx[8];
    __shared__ __align__(16) u32 s_h1[8][H1W];     // per-wave ROUND-1 hists
    __shared__ __align__(16) u32 s_hist[3][256];   // shared hists, rounds 2-4
    __shared__ u32 s_statm[8];

    const float* traj_b = g_traj + (size_t)b*(M*T*2);
    const float* cov_b  = g_cov  + (size_t)b*(M*T*4);

    // ========== direct gathers FIRST (redundant per wave; oldest vmem ops) ====
    float myLogit = -1e30f;
    if (lane < M) myLogit = g_logits[b*M + lane];
    float selx[3], sely[3], cc0[3], cc1[3], cc2[3];
    #pragma unroll
    for (int r = 0; r < 3; ++r) {
        int i = lane + r*64;
        if (i < M*3) {
            int m = i/3, tt = i - (i/3)*3;
            float2 xy = ((const float2*)traj_b)[m*T + SEL[tt]];
            float4 cv = ((const float4*)cov_b)[m*T + SEL[tt]];
            selx[r]=xy.x; sely[r]=xy.y; cc0[r]=cv.x; cc1[r]=cv.y; cc2[r]=cv.w;
        }
    }

    // ========== DMA staging AFTER gathers, split 8 ways ==========
    __builtin_amdgcn_sched_barrier(0);
    {
        const char* gt = (const char*)traj_b + lane*16;
        char* lt = (char*)s_txy;
        #pragma unroll 2
        for (int k = wv; k < 30; k += 8)
            __builtin_amdgcn_global_load_lds(
                (const __attribute__((address_space(1))) u32*)(gt + k*1024),
                (__attribute__((address_space(3))) u32*)(lt + k*1024), 16, 0, 0);
        const char* gc = (const char*)cov_b + lane*16;
        char* lc = (char*)s_cv4;
        #pragma unroll 2
        for (int k = wv; k < 60; k += 8)
            __builtin_amdgcn_global_load_lds(
                (const __attribute__((address_space(1))) u32*)(gc + k*1024),
                (__attribute__((address_space(3))) u32*)(lc + k*1024), 16, 0, 0);
    }
    __builtin_amdgcn_sched_barrier(0);

    // ========== zero hists (replicas: 528 uint4; shared: 192 uint4) ==========
    {
        uint4* hz = (uint4*)&s_h1[0][0];           // 8*264 = 2112 u32 = 528 uint4
        hz[tid] = make_uint4(0,0,0,0);
        if (tid < 16) hz[512 + tid] = make_uint4(0,0,0,0);
        if (tid < 192) ((uint4*)&s_hist[0][0])[tid] = make_uint4(0,0,0,0);
    }

    // ========== stage selector data (redundant identical writes) ==========
    if (lane < M) s_logits[lane] = myLogit;
    #pragma unroll
    for (int r = 0; r < 3; ++r) {
        int i = lane + r*64;
        if (i < M*3) {
            int m = i/3, tt = i - (i/3)*3;
            s_tsel[m*6+tt*2+0] = selx[r];
            s_tsel[m*6+tt*2+1] = sely[r];
            s_d1[i] = selx[r]*selx[r] + sely[r]*sely[r];
            s_csel[i*4+0]=cc0[r]; s_csel[i*4+1]=cc1[r]; s_csel[i*4+2]=cc2[r]; s_csel[i*4+3]=0.f;
        }
    }

    // ========== softmax (in-wave, registers; redundant per wave) ==========
    float mx = myLogit;
    #pragma unroll
    for (int off = 32; off; off >>= 1) mx = fmaxf(mx, __shfl_xor(mx, off));
    float pe = (lane < M) ? __expf(myLogit - mx) : 0.f;
    float psum = pe;
    #pragma unroll
    for (int off = 32; off; off >>= 1) psum += __shfl_xor(psum, off);
    if (lane < M) s_probas[lane] = pe / psum;

    WGSYNC();   // staging + softmax + hist zeros visible to ALL waves

    // ========== SQUARED distance keys (split) + round-1 replica hist ==========
    u32 key[NK];
    const bool kv4 = (tid < MM - 4*NTH);   // tid < 256
    {
        u32* h1w = &s_h1[wv][0];
        #pragma unroll
        for (int j = 0; j < NK; ++j) {
            key[j] = 0xFFFFFFFFu;
            if ((j < 4) || kv4) {
                int e = tid + j*NTH;
                int m = e/M, n = e - (e/M)*M;
                float dot = s_tsel[m*6+4]*s_tsel[n*6+4] + s_tsel[m*6+5]*s_tsel[n*6+5];
                float v = s_d1[m*3+2] + s_d1[n*3+2] - 2.0f*dot;
                key[j] = __float_as_uint(fmaxf(v, 0.0f));  // nonneg: uint order == float order
                atomicAdd(&h1w[key[j] >> 24], 1u);
            }
        }
    }

    // ========== exact order stat 345: 4-round radix over split keys ==========
    int target = 345;
    u32 prefix = 0u, pmask = 0u, scnt = 0u;
    #pragma unroll 1
    for (int r = 0; r < 4; ++r) {
        const int shift = 24 - 8*r;
        if (r) {
            #pragma unroll
            for (int j = 0; j < NK; ++j) {
                if (((j < 4) || kv4) && (key[j] & pmask) == prefix)
                    atomicAdd(&s_hist[r-1][(key[j] >> shift) & 255u], 1u);
            }
        }
        WGSYNC();   // own atomics drained; all partials visible
        uint4 hv;
        if (r == 0) {
            hv = make_uint4(0,0,0,0);
            #pragma unroll
            for (int w = 0; w < 8; ++w) {
                uint4 hw = *(const uint4*)&s_h1[w][lane*4];
                hv.x += hw.x; hv.y += hw.y; hv.z += hw.z; hv.w += hw.w;
            }
        } else {
            hv = ((const uint4*)&s_hist[r-1][0])[lane];
        }
        u32 s4 = hv.x + hv.y + hv.z + hv.w;
        u32 cum = s4;
        #pragma unroll
        for (int off = 1; off < 64; off <<= 1) {
            u32 u = __shfl_up(cum, off);
            if (lane >= off) cum += u;
        }
        u64 bmask = __ballot(cum > (u32)target);
        int g = __builtin_ctzll(bmask);
        int dig = 0; u32 binstart = 0, bcnt = 0;
        if (lane == g) {
            u32 exc = cum - s4;
            int bi2 = lane*4;
            if (exc + hv.x > (u32)target)      { dig = bi2;   binstart = exc; bcnt = hv.x; }
            else { exc += hv.x;
                if (exc + hv.y > (u32)target)  { dig = bi2+1; binstart = exc; bcnt = hv.y; }
                else { exc += hv.y;
                    if (exc + hv.z > (u32)target) { dig = bi2+2; binstart = exc; bcnt = hv.z; }
                    else { exc += hv.z;            dig = bi2+3; binstart = exc; bcnt = hv.w; } } }
        }
        dig = __shfl(dig, g);
        binstart = (u32)__shfl((int)binstart, g);
        scnt = (u32)__shfl((int)bcnt, g);   // count in chosen bin (final r: #keys==k1)
        target -= (int)binstart;
        prefix |= ((u32)dig) << shift;
        pmask  |= (255u << shift);
    }
    const u32 k1 = prefix;                 // squared order stat 345
    const float v1f = sqrtf(__uint_as_float(k1));

    // ========== order stat 346: tie case free; else min-scan (block-uniform) ==
    // #keys <= k1 = (345 - target) + scnt; >= 347  <=>  scnt >= target+2.
    float v2f;
    if (scnt >= (u32)(target + 2)) {
        v2f = v1f;
    } else {
        u32 mng = 0xFFFFFFFFu;
        #pragma unroll
        for (int j = 0; j < NK; ++j) {     // invalid keys are 0xFFFFFFFF: no-ops
            if (key[j] > k1 && key[j] < mng) mng = key[j];
        }
        #pragma unroll
        for (int off = 32; off > 0; off >>= 1) {
            u32 mo = (u32)__shfl_down((int)mng, off);
            mng = (mo < mng) ? mo : mng;
        }
        if (lane == 0) s_statm[wv] = mng;
        WGSYNC();
        u32 mt = s_statm[0];
        #pragma unroll
        for (int w = 1; w < 8; ++w) { u32 x = s_statm[w]; mt = (x < mt) ? x : mt; }
        v2f = sqrtf(__uint_as_float(mt));
    }
    const float qi = 0.15f * 2303.0f;
    const float fr = qi - floorf(qi);
    const float thr = v1f*(1.0f - fr) + v2f*fr;

    // exact squared threshold: dthr = max{u : fl(sqrt(u)) <= thr}
    float dthr;
    {
        u32 ub = __float_as_uint(thr*thr);
        while (sqrtf(__uint_as_float(ub)) > thr) --ub;        // <=2 iters
        while (sqrtf(__uint_as_float(ub+1u)) <= thr) ++ub;    // <=2 iters
        dthr = __uint_as_float(ub);
    }

    // ========== adjacency, squared-space (split: ~4.5/lane) ==========
    #pragma unroll
    for (int j = 0; j < NK; ++j) {
        if ((j < 4) || kv4) {
            int e = tid + j*NTH;
            int m = e/M, n = e - (e/M)*M;
            float d0 = s_tsel[m*6+0]*s_tsel[n*6+0] + s_tsel[m*6+1]*s_tsel[n*6+1];
            float v0 = fmaxf(s_d1[m*3+0] + s_d1[n*3+0] - 2.0f*d0, 0.0f);
            float d1v = s_tsel[m*6+2]*s_tsel[n*6+2] + s_tsel[m*6+3]*s_tsel[n*6+3];
            float v1 = fmaxf(s_d1[m*3+1] + s_d1[n*3+1] - 2.0f*d1v, 0.0f);
            bool a = (__uint_as_float(key[j]) <= dthr) && (v0 <= dthr) && (v1 <= dthr);
            s_adj[e] = a ? 1.0f : 0.0f;
        }
    }
    WGSYNC();

    // ========== EM lane roles + loop-invariant register preloads ==========
    // (runs on waves 1-7 while wave 0 does greedy below -- free)
    const int mE = tid >> 3;           // 0..63 (E-step row)
    const int nE = tid & 7;            // 0..7  (E-step component)
    const bool eAct = (mE < M) && (nE < NF);
    const int gid = tid >> 3;          // M-step group id (18 active)
    const int sub = tid & 7;
    const int gn  = gid/3, gtt = gid - (gid/3)*3;      // valid when gid<18
    float tmE0=0.f,tmE1=0.f,tmE2=0.f,tmE3=0.f,tmE4=0.f,tmE5=0.f,probaE=0.f;
    if (mE < M) {
        float2 a0 = *(const float2*)&s_tsel[mE*6+0];
        float2 a1 = *(const float2*)&s_tsel[mE*6+2];
        float2 a2 = *(const float2*)&s_tsel[mE*6+4];
        tmE0=a0.x; tmE1=a0.y; tmE2=a1.x; tmE3=a1.y; tmE4=a2.x; tmE5=a2.y;
        probaE = s_probas[mE];
    }
    float Mx[6], My[6], Mc0[6], Mc1[6], Mc2[6];
    if (gid < 18) {
        #pragma unroll
        for (int k = 0; k < 6; ++k) {
            int mm = sub*6 + k;
            float2 xy = *(const float2*)&s_tsel[mm*6+gtt*2];
            float4 c4 = *(const float4*)&s_csel[(mm*3+gtt)*4];
            Mx[k]=xy.x; My[k]=xy.y; Mc0[k]=c4.x; Mc1[k]=c4.y; Mc2[k]=c4.z;
        }
    }

    // ========== greedy selection + EM init: WAVE 0 ONLY ==========
    if (wv == 0) {
        const int m = (lane < M) ? lane : (M-1);
        float base = 0.f;
        #pragma unroll
        for (int n = 0; n < M; ++n) base += s_adj[n*M+m] * s_probas[n];
        float worked = 1.f;
        #pragma unroll 1
        for (int k = 0; k < NF; ++k) {
            float sc = (lane < M) ? base*worked : -1.f;
            int bi = lane;
            #pragma unroll
            for (int off = 32; off; off >>= 1) {
                float so = __shfl_down(sc, off);
                int io = __shfl_down(bi, off);
                if (so > sc || (so == sc && io < bi)) { sc = so; bi = io; }
            }
            int amax = __shfl(bi, 0);   // first-max == jnp.argmax
            if (lane == 0) s_idx[k] = amax;
            worked *= (1.f - s_adj[amax*M+m]);
        }
        // EM init -> buffer 0 (own-wave s_idx writes: in-order visible)
        if (lane < NF) {
            float mx6 = -1e30f;
            #pragma unroll
            for (int j = 0; j < NF; ++j) mx6 = fmaxf(mx6, s_logits[s_idx[j]]);
            float sum6 = 0.f;
            #pragma unroll
            for (int j = 0; j < NF; ++j) sum6 += __expf(s_logits[s_idx[j]] - mx6);
            s_probas6[0][lane] = __expf(s_logits[s_idx[lane]] - mx6) / sum6;
        }
        if (lane < NF*3) {
            int n = lane/3, tt = lane - (lane/3)*3;
            int m0 = s_idx[n];
            s_t6sel[0][n*8+tt*2+0] = s_tsel[m0*6+tt*2+0];
            s_t6sel[0][n*8+tt*2+1] = s_tsel[m0*6+tt*2+1];
            float c00 = s_csel[(m0*3+tt)*4+0];
            float c01 = s_csel[(m0*3+tt)*4+1];
            float c11 = s_csel[(m0*3+tt)*4+2];
            float det = c00*c11 - c01*c01;
            float rdet = __fdividef(1.0f, det);
            s_prec[0][n*PRW+tt*3+0] =  c11*rdet;
            s_prec[0][n*PRW+tt*3+1] = -c01*rdet;
            s_prec[0][n*PRW+tt*3+2] =  c00*rdet;
            s_ld[0][n*4+tt] = __logf(det);
        }
    }
    WGSYNC();   // state[0] + s_idx visible to all waves

    // ========== EM loop: vectorized E-step + register-hoisted M-step ==========
    #pragma unroll 1
    for (int it = 0; it < EMIT; ++it) {
        const int cur = it & 1, nxt = cur ^ 1;

        // ---- E-step: one component per lane, 7 vector LDS reads ----
        float numv = 0.f;
        if (eAct) {
            const float* prB = &s_prec[cur][nE*PRW];
            float4 pr0 = *(const float4*)(prB);
            float4 pr1 = *(const float4*)(prB+4);
            float  pr8 = prB[8];
            float4 t60 = *(const float4*)&s_t6sel[cur][nE*8];
            float2 t62 = *(const float2*)&s_t6sel[cur][nE*8+4];
            float4 ldv = *(const float4*)&s_ld[cur][nE*4];
            float  p6v = s_probas6[cur][nE];
            float lsum = ldv.x + ldv.y + ldv.z;
            float dx0 = t60.x-tmE0, dy0 = t60.y-tmE1;
            float dx1 = t60.z-tmE2, dy1 = t60.w-tmE3;
            float dx2 = t62.x-tmE4, dy2 = t62.y-tmE5;
            float q = pr0.x*dx0*dx0 + 2.f*pr0.y*dx0*dy0 + pr0.z*dy0*dy0
                    + pr0.w*dx1*dx1 + 2.f*pr1.x*dx1*dy1 + pr1.y*dy1*dy1
                    + pr1.z*dx2*dx2 + 2.f*pr1.w*dx2*dy2 + pr8*dy2*dy2;
            numv = (__expf(-3.f*LOG2PI - 0.5f*lsum - 0.5f*q) + 1e-8f) * p6v;
        }
        float den = numv;                    // group-of-8 sum (lanes 6,7 = 0)
        den += __shfl_xor(den, 1);
        den += __shfl_xor(den, 2);
        den += __shfl_xor(den, 4);
        den += 1e-8f;
        if (eAct) s_PmT[nE*PMW + mE] = numv * __fdividef(probaE, den);
        if (it == EMIT-1) break;

        WGSYNC();   // s_PmT (cross-wave) visible to M-step groups

        // ---- selector M-step: P-only LDS reads (3x b64), hoisted constants ----
        if (gid < 18) {
            const float* pB = &s_PmT[gn*PMW + sub*6];
            float2 p01 = *(const float2*)(pB);
            float2 p23 = *(const float2*)(pB+2);
            float2 p45 = *(const float2*)(pB+4);
            float pv[6] = {p01.x, p01.y, p23.x, p23.y, p45.x, p45.y};
            float SP=0,S1x=0,S1y=0,Sxx=0,Sxy=0,Syy=0,C0=0,C1=0,C2=0;
            #pragma unroll
            for (int k = 0; k < 6; ++k) {
                float p = pv[k];
                float x = Mx[k], y = My[k];
                SP += p; S1x += p*x; S1y += p*y;
                Sxx += p*x*x; Sxy += p*x*y; Syy += p*y*y;
                C0 += p*Mc0[k]; C1 += p*Mc1[k]; C2 += p*Mc2[k];
            }
            #define R8(v) { v += __shfl_down(v,4); v += __shfl_down(v,2); v += __shfl_down(v,1); }
            R8(SP) R8(S1x) R8(S1y) R8(Sxx) R8(Sxy) R8(Syy) R8(C0) R8(C1) R8(C2)
            #undef R8
            if (sub == 0) {
                float p6 = SP;
                float tx = __fdividef(S1x, p6), ty = __fdividef(S1y, p6);
                float rp = __fdividef(1.0f, p6);
                float c00 = (C0 + (Sxx - S1x*tx)) * rp;
                float c01 = (C1 + (Sxy - S1x*ty)) * rp;
                float c11 = (C2 + (Syy - S1y*ty)) * rp;
                float det = c00*c11 - c01*c01;
                float rdet = __fdividef(1.0f, det);
                s_prec[nxt][gn*PRW+gtt*3+0] =  c11*rdet;
                s_prec[nxt][gn*PRW+gtt*3+1] = -c01*rdet;
                s_prec[nxt][gn*PRW+gtt*3+2] =  c00*rdet;
                s_ld[nxt][gn*4+gtt] = __logf(det);
                s_t6sel[nxt][gn*8+gtt*2+0] = tx;
                s_t6sel[nxt][gn*8+gtt*2+1] = ty;
                if (gtt == 0) s_probas6[nxt][gn] = SP;
            }
        }
        WGSYNC();   // state[nxt] visible; DMA (vmcnt) stays in flight
    }

    // ========== full sync: DMA + last E-step visible ==========
    WGSYNC_ALL();

    // ========== final full-T M-step: 240 items x 2 lanes (24-deep loops) =====
    float*  out_p = g_out;
    float2* out_t = (float2*)(g_out + BATCH*NF);
    float4* out_c = (float4*)(g_out + BATCH*NF + BATCH*NF*T*2);
    if (lane < 60) {
        int item = wv*30 + (lane >> 1);   // 0..239 = (t, third)
        int half = lane & 1;              // mm range split across lane pair
        int t = item/3, third = item - (item/3)*3;
        int nA = third*2, nB = nA + 1;
        float SPa=0,S1xa=0,S1ya=0,Sxxa=0,Sxya=0,Syya=0,C00a=0,C01a=0,C11a=0;
        float SPb=0,S1xb=0,S1yb=0,Sxxb=0,Sxyb=0,Syyb=0,C00b=0,C01b=0,C11b=0;
        const int m0 = half*24;
        #pragma unroll 4
        for (int k = 0; k < 24; ++k) {
            int mm = m0 + k;
            float2 xy = ((const float2*)s_txy)[mm*T + t];
            float4 c4 = ((const float4*)s_cv4)[mm*T + t];
            float pa = s_PmT[nA*PMW + mm];
            float pb = s_PmT[nB*PMW + mm];
            float xx = xy.x*xy.x, xyv = xy.x*xy.y, yy = xy.y*xy.y;
            SPa+=pa; S1xa+=pa*xy.x; S1ya+=pa*xy.y;
            Sxxa+=pa*xx; Sxya+=pa*xyv; Syya+=pa*yy;
            C00a+=pa*c4.x; C01a+=pa*c4.y; C11a+=pa*c4.w;
            SPb+=pb; S1xb+=pb*xy.x; S1yb+=pb*xy.y;
            Sxxb+=pb*xx; Sxyb+=pb*xyv; Syyb+=pb*yy;
            C00b+=pb*c4.x; C01b+=pb*c4.y; C11b+=pb*c4.w;
        }
        // combine lane pair: both lanes end with full sums
        #define CX(v) v += __shfl_xor(v, 1);
        CX(SPa) CX(S1xa) CX(S1ya) CX(Sxxa) CX(Sxya) CX(Syya) CX(C00a) CX(C01a) CX(C11a)
        CX(SPb) CX(S1xb) CX(S1yb) CX(Sxxb) CX(Sxyb) CX(Syyb) CX(C00b) CX(C01b) CX(C11b)
        #undef CX
        if (half == 0) {
            float p6 = SPa;
            float tx = __fdividef(S1xa, p6), ty = __fdividef(S1ya, p6);
            float rp = __fdividef(1.0f, p6);
            float c00 = (C00a + (Sxxa - S1xa*tx)) * rp;
            float c01 = (C01a + (Sxya - S1xa*ty)) * rp;
            float c11 = (C11a + (Syya - S1ya*ty)) * rp;
            size_t o = (size_t)(b*NF + nA)*T + t;
            out_t[o] = make_float2(tx, ty);
            out_c[o] = make_float4(c00, c01, c01, c11);
        } else {
            float p6 = SPb;
            float tx = __fdividef(S1xb, p6), ty = __fdividef(S1yb, p6);
            float rp = __fdividef(1.0f, p6);
            float c00 = (C00b + (Sxxb - S1xb*tx)) * rp;
            float c01 = (C01b + (Sxyb - S1xb*ty)) * rp;
            float c11 = (C11b + (Syyb - S1yb*ty)) * rp;
            size_t o = (size_t)(b*NF + nB)*T + t;
            out_t[o] = make_float2(tx, ty);
            out_c[o] = make_float4(c00, c01, c01, c11);
        }
    }
    if (wv == 0 && lane < NF) {
        float sp = 0.f;
        #pragma unroll
        for (int j = 0; j < 24; ++j) {
            float2 v = *(const float2*)&s_PmT[lane*PMW + 2*j];
            sp += v.x; sp += v.y;
        }
        out_p[b*NF + lane] = sp;
    }
}

extern "C" void kernel_launch(void* const* d_in, const int* in_sizes, int n_in,
                              void* d_out, int out_size, void* d_ws, size_t ws_size,
                              hipStream_t stream) {
    const float* logits = (const float*)d_in[0];
    const float* traj   = (const float*)d_in[1];
    const float* cov    = (const float*)d_in[2];
    float* out = (float*)d_out;
    em_kernel<<<dim3(BATCH), dim3(NTH), 0, stream>>>(logits, traj, cov, out);
}

// Round 6
// 94.984 us; speedup vs baseline: 1.0574x; 1.0356x over previous
//
#include <hip/hip_runtime.h>
#include <math.h>

#define BATCH 256
#define M 48
#define T 80
#define NF 6
#define EMIT 10
#define MM (M*M)        // 2304
#define NTH 512         // 8 waves/block -> 2 waves/SIMD
#define NK 5            // ceil(2304/512); 5th key valid only for tid<256
#define PMW 52          // padded row stride of transposed P (bank spread)
#define H1W 264         // replica hist stride (264%32=8 -> bank-spread replicas)
#define PRW 20          // s_prec per-component stride (80B: conflict-free quads)
#define LOG2PI 1.8378770664093453f

typedef unsigned int u32;
typedef unsigned long long u64;

// Raw workgroup sync: drains LDS (lgkm) only -- async global_load_lds DMA
// (vmcnt) stays in flight. "memory" clobber stops compiler caching LDS in regs.
#define WGSYNC()     __asm__ __volatile__("s_waitcnt lgkmcnt(0)\ns_barrier" ::: "memory")
#define WGSYNC_ALL() __asm__ __volatile__("s_waitcnt vmcnt(0) lgkmcnt(0)\ns_barrier" ::: "memory")

// ---- DPP cross-lane (VALU, replaces ds_bpermute shuffles) ----
// ctrl: 0xB1 quad xor1 | 0x4E quad xor2 | 0x141 row_half_mirror
//       0x111/2/4/8 row_shr:N | 0x142 row_bcast:15 | 0x143 row_bcast:31
#define DPPF0(v, ctrl) __int_as_float(__builtin_amdgcn_update_dpp(0, __float_as_int(v), ctrl, 0xF, 0xF, true))
#define DPPU0(v, ctrl) ((u32)__builtin_amdgcn_update_dpp(0, (int)(v), ctrl, 0xF, 0xF, true))
#define DPPFS(v, ctrl) __int_as_float(__builtin_amdgcn_update_dpp(__float_as_int(v), __float_as_int(v), ctrl, 0xF, 0xF, false))
#define DPPIS(v, ctrl) __builtin_amdgcn_update_dpp((v), (v), ctrl, 0xF, 0xF, false)
// exact 8-group sum at lanes 7/15 of each row (zero-fill; pollution lanes never feed 7/15)
#define R8D(v) { v += DPPF0(v, 0x111); v += DPPF0(v, 0x112); v += DPPF0(v, 0x114); }
// pair sum (lane i ^ 1), both lanes get it
#define CXD(v) v += DPPF0(v, 0xB1);

// 8 waves/block. SHUFFLE->DPP this round (arithmetic identical): all
// literal-offset __shfl_* (ds_bpermute, ~35cyc DS-pipe each) become DPP VALU
// ops: M-step 8-group sums (consumer sub 0->7), E-step den (quad xor1/xor2 +
// half_mirror, all-lane), radix scan (row_shr + masked row_bcast), greedy
// argmax / softmax / 346-min (reduce-to-lane-63 + readlane), final-M pair
// combine (quad xor1). Uniform broadcasts via readlane (SGPR) not bpermute.
__global__ __launch_bounds__(NTH, 1)
void em_kernel(const float* __restrict__ g_logits,
               const float* __restrict__ g_traj,
               const float* __restrict__ g_cov,
               float* __restrict__ g_out)
{
    const int b = blockIdx.x;
    const int tid = threadIdx.x;
    const int lane = tid & 63;
    const int wv = tid >> 6;          // 0..7
    const int SEL[3] = {29, 49, 79};

    // ---- LDS ~117 KB ----
    __shared__ __align__(16) float s_txy[M*T*2];   // staged traj (DMA)
    __shared__ __align__(16) float s_cv4[M*T*4];   // staged cov (DMA)
    __shared__ float s_adj[MM];
    __shared__ float s_logits[M];
    __shared__ float s_probas[M];
    __shared__ float s_tsel[M*6];                  // [m][tt][d]
    __shared__ float s_d1[M*3];
    __shared__ __align__(16) float s_csel[M*3*4];  // [m][tt]{c00,c01,c11,pad}
    __shared__ __align__(16) float s_PmT[NF*PMW];  // TRANSPOSED P: [n][m], stride 52
    __shared__ __align__(16) float s_t6sel[2][NF*8];   // ping-pong, stride 8/comp
    __shared__ float s_probas6[2][NF];
    __shared__ __align__(16) float s_prec[2][NF*PRW];  // stride 20/comp (9 used)
    __shared__ __align__(16) float s_ld[2][NF*4];      // stride 4/comp (3 used)
    __shared__ int   s_idx[8];
    __shared__ __align__(16) u32 s_h1[8][H1W];     // per-wave ROUND-1 hists
    __shared__ __align__(16) u32 s_hist[3][256];   // shared hists, rounds 2-4
    __shared__ u32 s_statm[8];

    const float* traj_b = g_traj + (size_t)b*(M*T*2);
    const float* cov_b  = g_cov  + (size_t)b*(M*T*4);

    // ========== direct gathers FIRST (redundant per wave; oldest vmem ops) ====
    float myLogit = -1e30f;
    if (lane < M) myLogit = g_logits[b*M + lane];
    float selx[3], sely[3], cc0[3], cc1[3], cc2[3];
    #pragma unroll
    for (int r = 0; r < 3; ++r) {
        int i = lane + r*64;
        if (i < M*3) {
            int m = i/3, tt = i - (i/3)*3;
            float2 xy = ((const float2*)traj_b)[m*T + SEL[tt]];
            float4 cv = ((const float4*)cov_b)[m*T + SEL[tt]];
            selx[r]=xy.x; sely[r]=xy.y; cc0[r]=cv.x; cc1[r]=cv.y; cc2[r]=cv.w;
        }
    }

    // ========== DMA staging AFTER gathers, split 8 ways ==========
    __builtin_amdgcn_sched_barrier(0);
    {
        const char* gt = (const char*)traj_b + lane*16;
        char* lt = (char*)s_txy;
        #pragma unroll 2
        for (int k = wv; k < 30; k += 8)
            __builtin_amdgcn_global_load_lds(
                (const __attribute__((address_space(1))) u32*)(gt + k*1024),
                (__attribute__((address_space(3))) u32*)(lt + k*1024), 16, 0, 0);
        const char* gc = (const char*)cov_b + lane*16;
        char* lc = (char*)s_cv4;
        #pragma unroll 2
        for (int k = wv; k < 60; k += 8)
            __builtin_amdgcn_global_load_lds(
                (const __attribute__((address_space(1))) u32*)(gc + k*1024),
                (__attribute__((address_space(3))) u32*)(lc + k*1024), 16, 0, 0);
    }
    __builtin_amdgcn_sched_barrier(0);

    // ========== zero hists (replicas: 528 uint4; shared: 192 uint4) ==========
    {
        uint4* hz = (uint4*)&s_h1[0][0];           // 8*264 = 2112 u32 = 528 uint4
        hz[tid] = make_uint4(0,0,0,0);
        if (tid < 16) hz[512 + tid] = make_uint4(0,0,0,0);
        if (tid < 192) ((uint4*)&s_hist[0][0])[tid] = make_uint4(0,0,0,0);
    }

    // ========== stage selector data (redundant identical writes) ==========
    if (lane < M) s_logits[lane] = myLogit;
    #pragma unroll
    for (int r = 0; r < 3; ++r) {
        int i = lane + r*64;
        if (i < M*3) {
            int m = i/3, tt = i - (i/3)*3;
            s_tsel[m*6+tt*2+0] = selx[r];
            s_tsel[m*6+tt*2+1] = sely[r];
            s_d1[i] = selx[r]*selx[r] + sely[r]*sely[r];
            s_csel[i*4+0]=cc0[r]; s_csel[i*4+1]=cc1[r]; s_csel[i*4+2]=cc2[r]; s_csel[i*4+3]=0.f;
        }
    }

    // ========== softmax (DPP reduce-to-63 + readlane; redundant per wave) =====
    float mx = myLogit;
    #define MSTEP(ctrl) { float t_ = DPPFS(mx, ctrl); mx = fmaxf(mx, t_); }
    MSTEP(0x111) MSTEP(0x112) MSTEP(0x114) MSTEP(0x118) MSTEP(0x142) MSTEP(0x143)
    #undef MSTEP
    mx = __int_as_float(__builtin_amdgcn_readlane(__float_as_int(mx), 63));
    float pe = (lane < M) ? __expf(myLogit - mx) : 0.f;
    float psum = pe;
    psum += DPPF0(psum, 0x111);
    psum += DPPF0(psum, 0x112);
    psum += DPPF0(psum, 0x114);
    psum += DPPF0(psum, 0x118);
    psum += __int_as_float(__builtin_amdgcn_update_dpp(0, __float_as_int(psum), 0x142, 0xa, 0xF, false));
    psum += __int_as_float(__builtin_amdgcn_update_dpp(0, __float_as_int(psum), 0x143, 0xc, 0xF, false));
    psum = __int_as_float(__builtin_amdgcn_readlane(__float_as_int(psum), 63));
    if (lane < M) s_probas[lane] = pe / psum;

    WGSYNC();   // staging + softmax + hist zeros visible to ALL waves

    // ========== SQUARED distance keys (split) + round-1 replica hist ==========
    u32 key[NK];
    const bool kv4 = (tid < MM - 4*NTH);   // tid < 256
    {
        u32* h1w = &s_h1[wv][0];
        #pragma unroll
        for (int j = 0; j < NK; ++j) {
            key[j] = 0xFFFFFFFFu;
            if ((j < 4) || kv4) {
                int e = tid + j*NTH;
                int m = e/M, n = e - (e/M)*M;
                float dot = s_tsel[m*6+4]*s_tsel[n*6+4] + s_tsel[m*6+5]*s_tsel[n*6+5];
                float v = s_d1[m*3+2] + s_d1[n*3+2] - 2.0f*dot;
                key[j] = __float_as_uint(fmaxf(v, 0.0f));  // nonneg: uint order == float order
                atomicAdd(&h1w[key[j] >> 24], 1u);
            }
        }
    }

    // ========== exact order stat 345: 4-round radix over split keys ==========
    int target = 345;
    u32 prefix = 0u, pmask = 0u, scnt = 0u;
    #pragma unroll 1
    for (int r = 0; r < 4; ++r) {
        const int shift = 24 - 8*r;
        if (r) {
            #pragma unroll
            for (int j = 0; j < NK; ++j) {
                if (((j < 4) || kv4) && (key[j] & pmask) == prefix)
                    atomicAdd(&s_hist[r-1][(key[j] >> shift) & 255u], 1u);
            }
        }
        WGSYNC();   // own atomics drained; all partials visible
        uint4 hv;
        if (r == 0) {
            hv = make_uint4(0,0,0,0);
            #pragma unroll
            for (int w = 0; w < 8; ++w) {
                uint4 hw = *(const uint4*)&s_h1[w][lane*4];
                hv.x += hw.x; hv.y += hw.y; hv.z += hw.z; hv.w += hw.w;
            }
        } else {
            hv = ((const uint4*)&s_hist[r-1][0])[lane];
        }
        u32 s4 = hv.x + hv.y + hv.z + hv.w;
        // DPP inclusive scan (row_shr x4 + masked row_bcast combine)
        u32 cum = s4;
        cum += DPPU0(cum, 0x111);
        cum += DPPU0(cum, 0x112);
        cum += DPPU0(cum, 0x114);
        cum += DPPU0(cum, 0x118);
        cum += (u32)__builtin_amdgcn_update_dpp(0, (int)cum, 0x142, 0xa, 0xF, false);
        cum += (u32)__builtin_amdgcn_update_dpp(0, (int)cum, 0x143, 0xc, 0xF, false);
        u64 bmask = __ballot(cum > (u32)target);
        int g = __builtin_ctzll(bmask);
        int dig = 0; u32 binstart = 0, bcnt = 0;
        if (lane == g) {
            u32 exc = cum - s4;
            int bi2 = lane*4;
            if (exc + hv.x > (u32)target)      { dig = bi2;   binstart = exc; bcnt = hv.x; }
            else { exc += hv.x;
                if (exc + hv.y > (u32)target)  { dig = bi2+1; binstart = exc; bcnt = hv.y; }
                else { exc += hv.y;
                    if (exc + hv.z > (u32)target) { dig = bi2+2; binstart = exc; bcnt = hv.z; }
                    else { exc += hv.z;            dig = bi2+3; binstart = exc; bcnt = hv.w; } } }
        }
        dig      = __builtin_amdgcn_readlane(dig, g);            // g is uniform
        binstart = (u32)__builtin_amdgcn_readlane((int)binstart, g);
        scnt     = (u32)__builtin_amdgcn_readlane((int)bcnt, g); // final r: #keys==k1
        target -= (int)binstart;
        prefix |= ((u32)dig) << shift;
        pmask  |= (255u << shift);
    }
    const u32 k1 = prefix;                 // squared order stat 345
    const float v1f = sqrtf(__uint_as_float(k1));

    // ========== order stat 346: tie case free; else min-scan (block-uniform) ==
    float v2f;
    if (scnt >= (u32)(target + 2)) {
        v2f = v1f;
    } else {
        u32 mng = 0xFFFFFFFFu;
        #pragma unroll
        for (int j = 0; j < NK; ++j) {     // invalid keys are 0xFFFFFFFF: no-ops
            if (key[j] > k1 && key[j] < mng) mng = key[j];
        }
        #define NSTEP(ctrl) { u32 t_ = (u32)DPPIS((int)mng, ctrl); mng = (t_ < mng) ? t_ : mng; }
        NSTEP(0x111) NSTEP(0x112) NSTEP(0x114) NSTEP(0x118) NSTEP(0x142) NSTEP(0x143)
        #undef NSTEP
        if (lane == 63) s_statm[wv] = mng;
        WGSYNC();
        u32 mt = s_statm[0];
        #pragma unroll
        for (int w = 1; w < 8; ++w) { u32 x = s_statm[w]; mt = (x < mt) ? x : mt; }
        v2f = sqrtf(__uint_as_float(mt));
    }
    const float qi = 0.15f * 2303.0f;
    const float fr = qi - floorf(qi);
    const float thr = v1f*(1.0f - fr) + v2f*fr;

    // exact squared threshold: dthr = max{u : fl(sqrt(u)) <= thr}
    float dthr;
    {
        u32 ub = __float_as_uint(thr*thr);
        while (sqrtf(__uint_as_float(ub)) > thr) --ub;        // <=2 iters
        while (sqrtf(__uint_as_float(ub+1u)) <= thr) ++ub;    // <=2 iters
        dthr = __uint_as_float(ub);
    }

    // ========== adjacency, squared-space (split: ~4.5/lane) ==========
    #pragma unroll
    for (int j = 0; j < NK; ++j) {
        if ((j < 4) || kv4) {
            int e = tid + j*NTH;
            int m = e/M, n = e - (e/M)*M;
            float d0 = s_tsel[m*6+0]*s_tsel[n*6+0] + s_tsel[m*6+1]*s_tsel[n*6+1];
            float v0 = fmaxf(s_d1[m*3+0] + s_d1[n*3+0] - 2.0f*d0, 0.0f);
            float d1v = s_tsel[m*6+2]*s_tsel[n*6+2] + s_tsel[m*6+3]*s_tsel[n*6+3];
            float v1 = fmaxf(s_d1[m*3+1] + s_d1[n*3+1] - 2.0f*d1v, 0.0f);
            bool a = (__uint_as_float(key[j]) <= dthr) && (v0 <= dthr) && (v1 <= dthr);
            s_adj[e] = a ? 1.0f : 0.0f;
        }
    }
    WGSYNC();

    // ========== EM lane roles + loop-invariant register preloads ==========
    // (runs on waves 1-7 while wave 0 does greedy below -- free)
    const int mE = tid >> 3;           // 0..63 (E-step row)
    const int nE = tid & 7;            // 0..7  (E-step component)
    const bool eAct = (mE < M) && (nE < NF);
    const int gid = tid >> 3;          // M-step group id (18 active)
    const int sub = tid & 7;
    const int gn  = gid/3, gtt = gid - (gid/3)*3;      // valid when gid<18
    float tmE0=0.f,tmE1=0.f,tmE2=0.f,tmE3=0.f,tmE4=0.f,tmE5=0.f,probaE=0.f;
    if (mE < M) {
        float2 a0 = *(const float2*)&s_tsel[mE*6+0];
        float2 a1 = *(const float2*)&s_tsel[mE*6+2];
        float2 a2 = *(const float2*)&s_tsel[mE*6+4];
        tmE0=a0.x; tmE1=a0.y; tmE2=a1.x; tmE3=a1.y; tmE4=a2.x; tmE5=a2.y;
        probaE = s_probas[mE];
    }
    float Mx[6], My[6], Mc0[6], Mc1[6], Mc2[6];
    if (gid < 18) {
        #pragma unroll
        for (int k = 0; k < 6; ++k) {
            int mm = sub*6 + k;
            float2 xy = *(const float2*)&s_tsel[mm*6+gtt*2];
            float4 c4 = *(const float4*)&s_csel[(mm*3+gtt)*4];
            Mx[k]=xy.x; My[k]=xy.y; Mc0[k]=c4.x; Mc1[k]=c4.y; Mc2[k]=c4.z;
        }
    }

    // ========== greedy selection + EM init: WAVE 0 ONLY ==========
    if (wv == 0) {
        const int m = (lane < M) ? lane : (M-1);
        float base = 0.f;
        #pragma unroll
        for (int n = 0; n < M; ++n) base += s_adj[n*M+m] * s_probas[n];
        float worked = 1.f;
        #pragma unroll 1
        for (int k = 0; k < NF; ++k) {
            float sc = (lane < M) ? base*worked : -1.f;
            int bi = lane;
            // DPP argmax to lane 63 (old=self: OOR/non-target lanes no-op);
            // combine keeps smaller index on ties == first-max == jnp.argmax
            #define ASTEP(ctrl) { \
                float so = DPPFS(sc, ctrl); \
                int   io = DPPIS(bi, ctrl); \
                if (so > sc || (so == sc && io < bi)) { sc = so; bi = io; } }
            ASTEP(0x111) ASTEP(0x112) ASTEP(0x114) ASTEP(0x118) ASTEP(0x142) ASTEP(0x143)
            #undef ASTEP
            int amax = __builtin_amdgcn_readlane(bi, 63);
            if (lane == 0) s_idx[k] = amax;
            worked *= (1.f - s_adj[amax*M+m]);
        }
        // EM init -> buffer 0 (own-wave s_idx writes: in-order visible)
        if (lane < NF) {
            float mx6 = -1e30f;
            #pragma unroll
            for (int j = 0; j < NF; ++j) mx6 = fmaxf(mx6, s_logits[s_idx[j]]);
            float sum6 = 0.f;
            #pragma unroll
            for (int j = 0; j < NF; ++j) sum6 += __expf(s_logits[s_idx[j]] - mx6);
            s_probas6[0][lane] = __expf(s_logits[s_idx[lane]] - mx6) / sum6;
        }
        if (lane < NF*3) {
            int n = lane/3, tt = lane - (lane/3)*3;
            int m0 = s_idx[n];
            s_t6sel[0][n*8+tt*2+0] = s_tsel[m0*6+tt*2+0];
            s_t6sel[0][n*8+tt*2+1] = s_tsel[m0*6+tt*2+1];
            float c00 = s_csel[(m0*3+tt)*4+0];
            float c01 = s_csel[(m0*3+tt)*4+1];
            float c11 = s_csel[(m0*3+tt)*4+2];
            float det = c00*c11 - c01*c01;
            float rdet = __fdividef(1.0f, det);
            s_prec[0][n*PRW+tt*3+0] =  c11*rdet;
            s_prec[0][n*PRW+tt*3+1] = -c01*rdet;
            s_prec[0][n*PRW+tt*3+2] =  c00*rdet;
            s_ld[0][n*4+tt] = __logf(det);
        }
    }
    WGSYNC();   // state[0] + s_idx visible to all waves

    // ========== EM loop: vectorized E-step + register-hoisted M-step ==========
    #pragma unroll 1
    for (int it = 0; it < EMIT; ++it) {
        const int cur = it & 1, nxt = cur ^ 1;

        // ---- E-step: one component per lane, 7 vector LDS reads ----
        float numv = 0.f;
        if (eAct) {
            const float* prB = &s_prec[cur][nE*PRW];
            float4 pr0 = *(const float4*)(prB);
            float4 pr1 = *(const float4*)(prB+4);
            float  pr8 = prB[8];
            float4 t60 = *(const float4*)&s_t6sel[cur][nE*8];
            float2 t62 = *(const float2*)&s_t6sel[cur][nE*8+4];
            float4 ldv = *(const float4*)&s_ld[cur][nE*4];
            float  p6v = s_probas6[cur][nE];
            float lsum = ldv.x + ldv.y + ldv.z;
            float dx0 = t60.x-tmE0, dy0 = t60.y-tmE1;
            float dx1 = t60.z-tmE2, dy1 = t60.w-tmE3;
            float dx2 = t62.x-tmE4, dy2 = t62.y-tmE5;
            float q = pr0.x*dx0*dx0 + 2.f*pr0.y*dx0*dy0 + pr0.z*dy0*dy0
                    + pr0.w*dx1*dx1 + 2.f*pr1.x*dx1*dy1 + pr1.y*dy1*dy1
                    + pr1.z*dx2*dx2 + 2.f*pr1.w*dx2*dy2 + pr8*dy2*dy2;
            numv = (__expf(-3.f*LOG2PI - 0.5f*lsum - 0.5f*q) + 1e-8f) * p6v;
        }
        // group-of-8 sum, ALL lanes, pure DPP (lanes 6,7 contribute 0)
        float den = numv;
        den += DPPF0(den, 0xB1);    // + lane^1 (quad)
        den += DPPF0(den, 0x4E);    // + lane^2 (quad) -> quad sums
        den += DPPF0(den, 0x141);   // + other quad (row_half_mirror)
        den += 1e-8f;
        if (eAct) s_PmT[nE*PMW + mE] = numv * __fdividef(probaE, den);
        if (it == EMIT-1) break;

        WGSYNC();   // s_PmT (cross-wave) visible to M-step groups

        // ---- selector M-step: P-only LDS reads, DPP group sums (at sub 7) ----
        if (gid < 18) {
            const float* pB = &s_PmT[gn*PMW + sub*6];
            float2 p01 = *(const float2*)(pB);
            float2 p23 = *(const float2*)(pB+2);
            float2 p45 = *(const float2*)(pB+4);
            float pv[6] = {p01.x, p01.y, p23.x, p23.y, p45.x, p45.y};
            float SP=0,S1x=0,S1y=0,Sxx=0,Sxy=0,Syy=0,C0=0,C1=0,C2=0;
            #pragma unroll
            for (int k = 0; k < 6; ++k) {
                float p = pv[k];
                float x = Mx[k], y = My[k];
                SP += p; S1x += p*x; S1y += p*y;
                Sxx += p*x*x; Sxy += p*x*y; Syy += p*y*y;
                C0 += p*Mc0[k]; C1 += p*Mc1[k]; C2 += p*Mc2[k];
            }
            R8D(SP) R8D(S1x) R8D(S1y) R8D(Sxx) R8D(Sxy) R8D(Syy) R8D(C0) R8D(C1) R8D(C2)
            if (sub == 7) {                 // DPP group sum lands at lane 7
                float p6 = SP;
                float tx = __fdividef(S1x, p6), ty = __fdividef(S1y, p6);
                float rp = __fdividef(1.0f, p6);
                float c00 = (C0 + (Sxx - S1x*tx)) * rp;
                float c01 = (C1 + (Sxy - S1x*ty)) * rp;
                float c11 = (C2 + (Syy - S1y*ty)) * rp;
                float det = c00*c11 - c01*c01;
                float rdet = __fdividef(1.0f, det);
                s_prec[nxt][gn*PRW+gtt*3+0] =  c11*rdet;
                s_prec[nxt][gn*PRW+gtt*3+1] = -c01*rdet;
                s_prec[nxt][gn*PRW+gtt*3+2] =  c00*rdet;
                s_ld[nxt][gn*4+gtt] = __logf(det);
                s_t6sel[nxt][gn*8+gtt*2+0] = tx;
                s_t6sel[nxt][gn*8+gtt*2+1] = ty;
                if (gtt == 0) s_probas6[nxt][gn] = SP;
            }
        }
        WGSYNC();   // state[nxt] visible; DMA (vmcnt) stays in flight
    }

    // ========== full sync: DMA + last E-step visible ==========
    WGSYNC_ALL();

    // ========== final full-T M-step: 240 items x 2 lanes (24-deep loops) =====
    float*  out_p = g_out;
    float2* out_t = (float2*)(g_out + BATCH*NF);
    float4* out_c = (float4*)(g_out + BATCH*NF + BATCH*NF*T*2);
    if (lane < 60) {
        int item = wv*30 + (lane >> 1);   // 0..239 = (t, third)
        int half = lane & 1;              // mm range split across lane pair
        int t = item/3, third = item - (item/3)*3;
        int nA = third*2, nB = nA + 1;
        float SPa=0,S1xa=0,S1ya=0,Sxxa=0,Sxya=0,Syya=0,C00a=0,C01a=0,C11a=0;
        float SPb=0,S1xb=0,S1yb=0,Sxxb=0,Sxyb=0,Syyb=0,C00b=0,C01b=0,C11b=0;
        const int m0 = half*24;
        #pragma unroll 4
        for (int k = 0; k < 24; ++k) {
            int mm = m0 + k;
            float2 xy = ((const float2*)s_txy)[mm*T + t];
            float4 c4 = ((const float4*)s_cv4)[mm*T + t];
            float pa = s_PmT[nA*PMW + mm];
            float pb = s_PmT[nB*PMW + mm];
            float xx = xy.x*xy.x, xyv = xy.x*xy.y, yy = xy.y*xy.y;
            SPa+=pa; S1xa+=pa*xy.x; S1ya+=pa*xy.y;
            Sxxa+=pa*xx; Sxya+=pa*xyv; Syya+=pa*yy;
            C00a+=pa*c4.x; C01a+=pa*c4.y; C11a+=pa*c4.w;
            SPb+=pb; S1xb+=pb*xy.x; S1yb+=pb*xy.y;
            Sxxb+=pb*xx; Sxyb+=pb*xyv; Syyb+=pb*yy;
            C00b+=pb*c4.x; C01b+=pb*c4.y; C11b+=pb*c4.w;
        }
        // combine lane pair (quad_perm xor1 DPP): both lanes end with full sums
        CXD(SPa) CXD(S1xa) CXD(S1ya) CXD(Sxxa) CXD(Sxya) CXD(Syya) CXD(C00a) CXD(C01a) CXD(C11a)
        CXD(SPb) CXD(S1xb) CXD(S1yb) CXD(Sxxb) CXD(Sxyb) CXD(Syyb) CXD(C00b) CXD(C01b) CXD(C11b)
        if (half == 0) {
            float p6 = SPa;
            float tx = __fdividef(S1xa, p6), ty = __fdividef(S1ya, p6);
            float rp = __fdividef(1.0f, p6);
            float c00 = (C00a + (Sxxa - S1xa*tx)) * rp;
            float c01 = (C01a + (Sxya - S1xa*ty)) * rp;
            float c11 = (C11a + (Syya - S1ya*ty)) * rp;
            size_t o = (size_t)(b*NF + nA)*T + t;
            out_t[o] = make_float2(tx, ty);
            out_c[o] = make_float4(c00, c01, c01, c11);
        } else {
            float p6 = SPb;
            float tx = __fdividef(S1xb, p6), ty = __fdividef(S1yb, p6);
            float rp = __fdividef(1.0f, p6);
            float c00 = (C00b + (Sxxb - S1xb*tx)) * rp;
            float c01 = (C01b + (Sxyb - S1xb*ty)) * rp;
            float c11 = (C11b + (Syyb - S1yb*ty)) * rp;
            size_t o = (size_t)(b*NF + nB)*T + t;
            out_t[o] = make_float2(tx, ty);
            out_c[o] = make_float4(c00, c01, c01, c11);
        }
    }
    if (wv == 0 && lane < NF) {
        float sp = 0.f;
        #pragma unroll
        for (int j = 0; j < 24; ++j) {
            float2 v = *(const float2*)&s_PmT[lane*PMW + 2*j];
            sp += v.x; sp += v.y;
        }
        out_p[b*NF + lane] = sp;
    }
}

extern "C" void kernel_launch(void* const* d_in, const int* in_sizes, int n_in,
                              void* d_out, int out_size, void* d_ws, size_t ws_size,
                              hipStream_t stream) {
    const float* logits = (const float*)d_in[0];
    const float* traj   = (const float*)d_in[1];
    const float* cov    = (const float*)d_in[2];
    float* out = (float*)d_out;
    em_kernel<<<dim3(BATCH), dim3(NTH), 0, stream>>>(logits, traj, cov, out);
}